// Round 1
// baseline (2314.417 us; speedup 1.0000x reference)
//
#include <hip/hip_runtime.h>
#include <hip/hip_bf16.h>
#include <math.h>

#define N_NODES 50000
#define N_EDGES 800000
#define N_GRAPHS 256
#define DIM 64
#define EDIM 50
#define HDIM 128
#define NLAYER 4
#define ZDIM (2 * DIM + EDIM)  // 178

__device__ __forceinline__ float softplus_f(float x) {
    // numerically stable: max(x,0) + log1p(exp(-|x|))
    return fmaxf(x, 0.0f) + log1pf(__expf(-fabsf(x)));
}
__device__ __forceinline__ float sigmoid_f(float x) {
    return 1.0f / (1.0f + __expf(-x));
}

// h[n][d] = emb[x[n]][d]
__global__ void k_embed(const int* __restrict__ x, const float* __restrict__ emb,
                        float* __restrict__ h) {
    int i = blockIdx.x * 256 + threadIdx.x;  // over N*64 (exact)
    int n = i >> 6, d = i & 63;
    h[i] = emb[x[n] * DIM + d];
}

// Per-layer node-side matmuls:
//  dstpack[n][d][0] = sum_k h[n][k]*Wf[k][d]     + bf[d]
//  dstpack[n][d][1] = sum_k h[n][k]*Ws[k][d]     + bs[d]
//  srcpack[n][d][0] = sum_k h[n][k]*Wf[64+k][d]
//  srcpack[n][d][1] = sum_k h[n][k]*Ws[64+k][d]
__global__ __launch_bounds__(256) void k_nodemm(
    const float* __restrict__ h,
    const float* __restrict__ Wf, const float* __restrict__ bf,
    const float* __restrict__ Ws, const float* __restrict__ bs,
    float* __restrict__ dstpack, float* __restrict__ srcpack) {
    __shared__ float hs[64 * 68];
    int tid = threadIdx.x;
    int w = tid >> 6, d = tid & 63;
    int n0 = blockIdx.x * 64;
    for (int idx = tid; idx < 64 * 64; idx += 256) {
        int i = idx >> 6, k = idx & 63;
        int n = n0 + i;
        hs[i * 68 + k] = (n < N_NODES) ? h[n * DIM + k] : 0.0f;
    }
    __syncthreads();
    const float* Wsel = (w == 0 || w == 2) ? Wf : Ws;
    int row0 = (w < 2) ? 0 : 64;
    float wcol[64];
#pragma unroll
    for (int k = 0; k < 64; ++k) wcol[k] = Wsel[(row0 + k) * 64 + d];
    float bias = (w == 0) ? bf[d] : (w == 1) ? bs[d] : 0.0f;
    float* outp = (w < 2) ? dstpack : srcpack;
    int ch = w & 1;
    int nmax = min(64, N_NODES - n0);
    for (int i = 0; i < nmax; ++i) {
        float acc = bias;
#pragma unroll
        for (int k = 0; k < 64; k += 4) {
            float4 hv = *(const float4*)&hs[i * 68 + k];
            acc += hv.x * wcol[k] + hv.y * wcol[k + 1] + hv.z * wcol[k + 2] + hv.w * wcol[k + 3];
        }
        outp[(size_t)(n0 + i) * 128 + d * 2 + ch] = acc;
    }
}

// Edge messages + scatter-add.
// accf = dstpack[t][d][0] + srcpack[s][d][0] + sum_k e[k]*WfE[k][d]
// accs = dstpack[t][d][1] + srcpack[s][d][1] + sum_k e[k]*WsE[k][d]
// agg[t][d] += sigmoid(accf) * softplus(accs)
__global__ __launch_bounds__(256) void k_edge(
    const int* __restrict__ eidx,       // [2][E]
    const float* __restrict__ eattr,    // [E][50]
    const float* __restrict__ dstpack,  // [N][64][2]
    const float* __restrict__ srcpack,  // [N][64][2]
    const float* __restrict__ WfE,      // [50][64]
    const float* __restrict__ WsE,      // [50][64]
    float* __restrict__ agg) {          // [N][64]
    __shared__ float ea[64 * 52];
    __shared__ int sidx[64], didx[64];
    int tid = threadIdx.x;
    int w = tid >> 6, d = tid & 63;
    float wf[50], ws[50];
#pragma unroll
    for (int k = 0; k < 50; ++k) {
        wf[k] = WfE[k * 64 + d];
        ws[k] = WsE[k * 64 + d];
    }
    const float2* dp = (const float2*)dstpack;
    const float2* sp = (const float2*)srcpack;
    const int nChunks = N_EDGES / 64;
    for (int c = blockIdx.x; c < nChunks; c += gridDim.x) {
        int e0 = c * 64;
        __syncthreads();
        for (int idx = tid; idx < 64 * 50; idx += 256) {
            int i = idx / 50, k = idx - i * 50;
            ea[i * 52 + k] = eattr[(size_t)(e0 + i) * EDIM + k];
        }
        if (tid < 64) {
            sidx[tid] = eidx[e0 + tid];
            didx[tid] = eidx[N_EDGES + e0 + tid];
        }
        __syncthreads();
        for (int j = 0; j < 16; ++j) {
            int el = w * 16 + j;
            int s = sidx[el], t = didx[el];
            float2 dv = dp[(size_t)t * 64 + d];
            float2 sv = sp[(size_t)s * 64 + d];
            float accf = dv.x + sv.x;
            float accs = dv.y + sv.y;
#pragma unroll
            for (int k = 0; k < 48; k += 4) {
                float4 e4 = *(const float4*)&ea[el * 52 + k];
                accf += e4.x * wf[k] + e4.y * wf[k + 1] + e4.z * wf[k + 2] + e4.w * wf[k + 3];
                accs += e4.x * ws[k] + e4.y * ws[k + 1] + e4.z * ws[k + 2] + e4.w * ws[k + 3];
            }
            float2 e2 = *(const float2*)&ea[el * 52 + 48];
            accf += e2.x * wf[48] + e2.y * wf[49];
            accs += e2.x * ws[48] + e2.y * ws[49];
            float msg = sigmoid_f(accf) * softplus_f(accs);
            unsafeAtomicAdd(&agg[(size_t)t * 64 + d], msg);
        }
    }
}

// h = softplus(h + agg)
__global__ void k_update(float* __restrict__ h, const float* __restrict__ agg) {
    int i = blockIdx.x * 256 + threadIdx.x;
    h[i] = softplus_f(h[i] + agg[i]);
}

// pooled[g][d] += h[n][d]; counts[g] += 1
__global__ void k_pool(const float* __restrict__ h, const int* __restrict__ batch,
                       float* __restrict__ pooled, float* __restrict__ counts) {
    int i = blockIdx.x * 256 + threadIdx.x;
    int n = i >> 6, d = i & 63;
    int g = batch[n];
    unsafeAtomicAdd(&pooled[g * DIM + d], h[i]);
    if (d == 0) unsafeAtomicAdd(&counts[g], 1.0f);
}

// out[g] = relu(relu(pooled/cnt @ W1 + b1) @ W2 + b2) @ Wo + bo
__global__ __launch_bounds__(64) void k_mlp(
    const float* __restrict__ pooled, const float* __restrict__ counts,
    const float* __restrict__ W1, const float* __restrict__ b1,
    const float* __restrict__ W2, const float* __restrict__ b2,
    const float* __restrict__ Wo, const float* __restrict__ bo,
    float* __restrict__ out) {
    __shared__ float ps[64];
    __shared__ float h1[128];
    int g = blockIdx.x, lane = threadIdx.x;
    float c = fmaxf(counts[g], 1.0f);
    ps[lane] = pooled[g * DIM + lane] / c;
    __syncthreads();
#pragma unroll
    for (int rep = 0; rep < 2; ++rep) {
        int j = lane + rep * 64;
        float acc = b1[j];
        for (int k = 0; k < 64; ++k) acc += ps[k] * W1[k * HDIM + j];
        h1[j] = fmaxf(acc, 0.0f);
    }
    __syncthreads();
    float acc = b2[lane];
    for (int k = 0; k < 128; ++k) acc += h1[k] * W2[k * 64 + lane];
    float v = fmaxf(acc, 0.0f) * Wo[lane];
#pragma unroll
    for (int off = 32; off; off >>= 1) v += __shfl_down(v, off);
    if (lane == 0) out[g] = v + bo[0];
}

extern "C" void kernel_launch(void* const* d_in, const int* in_sizes, int n_in,
                              void* d_out, int out_size, void* d_ws, size_t ws_size,
                              hipStream_t stream) {
    const int* x = (const int*)d_in[0];
    const int* eidx = (const int*)d_in[1];
    const float* eattr = (const float*)d_in[2];
    const int* batch = (const int*)d_in[3];
    const float* emb = (const float*)d_in[4];
    const float* Wf = (const float*)d_in[5];   // [4][178][64]
    const float* bf = (const float*)d_in[6];   // [4][64]
    const float* Ws = (const float*)d_in[7];
    const float* bs = (const float*)d_in[8];
    const float* W1 = (const float*)d_in[9];   // [64][128]
    const float* b1 = (const float*)d_in[10];
    const float* W2 = (const float*)d_in[11];  // [128][64]
    const float* b2 = (const float*)d_in[12];
    const float* Wo = (const float*)d_in[13];  // [64][1]
    const float* bo = (const float*)d_in[14];
    float* out = (float*)d_out;

    char* p = (char*)d_ws;
    float* h = (float*)p;       p += (size_t)N_NODES * DIM * 4;
    float* dstpack = (float*)p; p += (size_t)N_NODES * 2 * DIM * 4;
    float* srcpack = (float*)p; p += (size_t)N_NODES * 2 * DIM * 4;
    float* agg = (float*)p;     p += (size_t)N_NODES * DIM * 4;
    float* pooled = (float*)p;  p += (size_t)N_GRAPHS * DIM * 4;
    float* counts = (float*)p;  p += (size_t)N_GRAPHS * 4;

    k_embed<<<N_NODES * DIM / 256, 256, 0, stream>>>(x, emb, h);
    for (int l = 0; l < NLAYER; ++l) {
        const float* Wfl = Wf + (size_t)l * ZDIM * DIM;
        const float* Wsl = Ws + (size_t)l * ZDIM * DIM;
        k_nodemm<<<(N_NODES + 63) / 64, 256, 0, stream>>>(
            h, Wfl, bf + l * DIM, Wsl, bs + l * DIM, dstpack, srcpack);
        hipMemsetAsync(agg, 0, (size_t)N_NODES * DIM * 4, stream);
        k_edge<<<2048, 256, 0, stream>>>(eidx, eattr, dstpack, srcpack,
                                         Wfl + 128 * DIM, Wsl + 128 * DIM, agg);
        k_update<<<N_NODES * DIM / 256, 256, 0, stream>>>(h, agg);
    }
    hipMemsetAsync(pooled, 0, ((size_t)N_GRAPHS * DIM + N_GRAPHS) * 4, stream);
    k_pool<<<N_NODES * DIM / 256, 256, 0, stream>>>(h, batch, pooled, counts);
    k_mlp<<<N_GRAPHS, 64, 0, stream>>>(pooled, counts, W1, b1, W2, b2, Wo, bo, out);
}

// Round 2
// 1484.735 us; speedup vs baseline: 1.5588x; 1.5588x over previous
//
#include <hip/hip_runtime.h>
#include <hip/hip_bf16.h>
#include <math.h>

#define N_NODES 50000
#define N_EDGES 800000
#define N_GRAPHS 256
#define DIM 64
#define EDIM 50
#define HDIM 128
#define NLAYER 4
#define ZDIM (2 * DIM + EDIM)  // 178

typedef __attribute__((ext_vector_type(8))) short short8v;
typedef __attribute__((ext_vector_type(16))) float f32x16;

__device__ __forceinline__ float softplus_f(float x) {
    return fmaxf(x, 0.0f) + log1pf(__expf(-fabsf(x)));
}

__device__ __forceinline__ short cvt_bf16(float f) {
    __hip_bfloat16 h = __float2bfloat16(f);
    return *reinterpret_cast<short*>(&h);
}

// h[n][d] = emb[x[n]][d]
__global__ void k_embed(const int* __restrict__ x, const float* __restrict__ emb,
                        float* __restrict__ h) {
    int i = blockIdx.x * 256 + threadIdx.x;  // over N*64 (exact)
    int n = i >> 6, d = i & 63;
    h[i] = emb[x[n] * DIM + d];
}

// Build bf16 edge-weight tiles for all layers:
// wcat[l][k][2*d+g] = (k<50) ? W_g[l][128+k][d] : 0   (k padded to 64)
__global__ void k_wcat(const float* __restrict__ Wf, const float* __restrict__ Ws,
                       short* __restrict__ wcat) {
    int i = blockIdx.x * 256 + threadIdx.x;  // over 4*64*128 = 32768
    int l = i >> 13;
    int rem = i & 8191;
    int k = rem >> 7;
    int colv = rem & 127;
    int d = colv >> 1, g = colv & 1;
    float v = 0.0f;
    if (k < 50) {
        const float* W = g ? Ws : Wf;
        v = W[((size_t)l * ZDIM + 128 + k) * 64 + d];
    }
    wcat[i] = cvt_bf16(v);
}

// Per-layer node-side matmuls (bias folded into dstpack):
//  dstpack[n][2*d+0] = sum_k h[n][k]*Wf[k][d] + bf[d]
//  dstpack[n][2*d+1] = sum_k h[n][k]*Ws[k][d] + bs[d]
//  srcpack[n][2*d+g] = sum_k h[n][k]*W_g[64+k][d]
__global__ __launch_bounds__(256) void k_nodemm(
    const float* __restrict__ h,
    const float* __restrict__ Wf, const float* __restrict__ bf,
    const float* __restrict__ Ws, const float* __restrict__ bs,
    float* __restrict__ dstpack, float* __restrict__ srcpack) {
    __shared__ float hs[64 * 68];
    int tid = threadIdx.x;
    int w = tid >> 6, d = tid & 63;
    int n0 = blockIdx.x * 64;
    for (int idx = tid; idx < 64 * 64; idx += 256) {
        int i = idx >> 6, k = idx & 63;
        int n = n0 + i;
        hs[i * 68 + k] = (n < N_NODES) ? h[n * DIM + k] : 0.0f;
    }
    __syncthreads();
    const float* Wsel = (w == 0 || w == 2) ? Wf : Ws;
    int row0 = (w < 2) ? 0 : 64;
    float wcol[64];
#pragma unroll
    for (int k = 0; k < 64; ++k) wcol[k] = Wsel[(row0 + k) * 64 + d];
    float bias = (w == 0) ? bf[d] : (w == 1) ? bs[d] : 0.0f;
    float* outp = (w < 2) ? dstpack : srcpack;
    int ch = w & 1;
    int nmax = min(64, N_NODES - n0);
    for (int i = 0; i < nmax; ++i) {
        float acc = bias;
#pragma unroll
        for (int k = 0; k < 64; k += 4) {
            float4 hv = *(const float4*)&hs[i * 68 + k];
            acc += hv.x * wcol[k] + hv.y * wcol[k + 1] + hv.z * wcol[k + 2] + hv.w * wcol[k + 3];
        }
        outp[(size_t)(n0 + i) * 128 + d * 2 + ch] = acc;
    }
}

// Edge kernel (MFMA): per 32-edge tile, 4 waves each compute a 32x32 slice of
// [32 edges] x [128 cols] where col = 2*d + gate. K = 64 (eattr padded 50->64).
// epilogue: pre = mfma + dstpack[t][col] + srcpack[s][col];
//           msg = sigmoid(pre_f) * softplus(pre_s) via shfl_xor(1); atomic to agg.
__global__ __launch_bounds__(256) void k_edge(
    const int* __restrict__ eidx,       // [2][E]
    const float* __restrict__ eattr,    // [E][50]
    const float* __restrict__ dstpack,  // [N][128]
    const float* __restrict__ srcpack,  // [N][128]
    const short* __restrict__ wcat_l,   // [64][128] bf16
    float* __restrict__ agg) {          // [N][64]
    int tid = threadIdx.x;
    int w = tid >> 6;        // wave 0..3 -> col slice
    int lane = tid & 63;
    int c = lane & 31;       // col within slice / edge row for A
    int h2 = lane >> 5;      // half-wave -> k-offset
    int col = w * 32 + c;

    // B fragments: b[kk][e] = wcat[kk*16 + 8*h2 + e][col], kk=0..3 (K=64)
    short8v bfr[4];
#pragma unroll
    for (int kk = 0; kk < 4; ++kk) {
#pragma unroll
        for (int e = 0; e < 8; ++e) {
            bfr[kk][e] = wcat_l[(kk * 16 + 8 * h2 + e) * 128 + col];
        }
    }

    const int nTiles = N_EDGES / 32;
    for (int tile = blockIdx.x; tile < nTiles; tile += gridDim.x) {
        int e0 = tile * 32;
        int myedge = e0 + c;
        int sl = eidx[myedge];             // src of edge (e0+c)
        int dl = eidx[N_EDGES + myedge];   // dst of edge (e0+c)

        // A fragments: a[kk][e] = bf16(eattr[e0+c][kk*16 + 8*h2 + e]) (0-pad k>=50)
        const float* erow = eattr + (size_t)myedge * EDIM;
        short8v afr[4];
#pragma unroll
        for (int kk = 0; kk < 3; ++kk) {
            int k0 = kk * 16 + 8 * h2;   // 0..40: fully in-bounds
#pragma unroll
            for (int p = 0; p < 4; ++p) {
                float2 v = *(const float2*)(erow + k0 + 2 * p);
                afr[kk][2 * p] = cvt_bf16(v.x);
                afr[kk][2 * p + 1] = cvt_bf16(v.y);
            }
        }
        {
            short8v a;
#pragma unroll
            for (int e = 0; e < 8; ++e) a[e] = 0;
            if (h2 == 0) {  // k = 48..55: only 48,49 valid
                float2 v = *(const float2*)(erow + 48);
                a[0] = cvt_bf16(v.x);
                a[1] = cvt_bf16(v.y);
            }
            afr[3] = a;
        }

        f32x16 acc;
#pragma unroll
        for (int i = 0; i < 16; ++i) acc[i] = 0.0f;
#pragma unroll
        for (int kk = 0; kk < 4; ++kk) {
            acc = __builtin_amdgcn_mfma_f32_32x32x16_bf16(afr[kk], bfr[kk], acc, 0, 0, 0);
        }

        // Epilogue: C/D layout (32x32): col = lane&31, row = (r&3)+8*(r>>2)+4*h2
#pragma unroll
        for (int r = 0; r < 16; ++r) {
            int row = (r & 3) + 8 * (r >> 2) + 4 * h2;
            int t = __shfl(dl, row);
            int s = __shfl(sl, row);
            float pre = acc[r] + dstpack[(size_t)t * 128 + col] + srcpack[(size_t)s * 128 + col];
            float e = __expf(-fabsf(pre));
            float inv = 1.0f / (1.0f + e);
            float sig = (pre >= 0.0f) ? inv : e * inv;
            float sp = fmaxf(pre, 0.0f) + __logf(1.0f + e);
            float mine = (c & 1) ? sp : sig;
            float partner = __shfl_xor(mine, 1);
            if (!(c & 1)) {
                unsafeAtomicAdd(&agg[(size_t)t * 64 + (col >> 1)], sig * partner);
            }
        }
    }
}

// h = softplus(h + agg)
__global__ void k_update(float* __restrict__ h, const float* __restrict__ agg) {
    int i = blockIdx.x * 256 + threadIdx.x;
    h[i] = softplus_f(h[i] + agg[i]);
}

// pooled[g][d] += h[n][d]; counts[g] += 1
__global__ void k_pool(const float* __restrict__ h, const int* __restrict__ batch,
                       float* __restrict__ pooled, float* __restrict__ counts) {
    int i = blockIdx.x * 256 + threadIdx.x;
    int n = i >> 6, d = i & 63;
    int g = batch[n];
    unsafeAtomicAdd(&pooled[g * DIM + d], h[i]);
    if (d == 0) unsafeAtomicAdd(&counts[g], 1.0f);
}

// out[g] = relu(relu(pooled/cnt @ W1 + b1) @ W2 + b2) @ Wo + bo
__global__ __launch_bounds__(64) void k_mlp(
    const float* __restrict__ pooled, const float* __restrict__ counts,
    const float* __restrict__ W1, const float* __restrict__ b1,
    const float* __restrict__ W2, const float* __restrict__ b2,
    const float* __restrict__ Wo, const float* __restrict__ bo,
    float* __restrict__ out) {
    __shared__ float ps[64];
    __shared__ float h1[128];
    int g = blockIdx.x, lane = threadIdx.x;
    float cnt = fmaxf(counts[g], 1.0f);
    ps[lane] = pooled[g * DIM + lane] / cnt;
    __syncthreads();
#pragma unroll
    for (int rep = 0; rep < 2; ++rep) {
        int j = lane + rep * 64;
        float acc = b1[j];
        for (int k = 0; k < 64; ++k) acc += ps[k] * W1[k * HDIM + j];
        h1[j] = fmaxf(acc, 0.0f);
    }
    __syncthreads();
    float acc = b2[lane];
    for (int k = 0; k < 128; ++k) acc += h1[k] * W2[k * 64 + lane];
    float v = fmaxf(acc, 0.0f) * Wo[lane];
#pragma unroll
    for (int off = 32; off; off >>= 1) v += __shfl_down(v, off);
    if (lane == 0) out[g] = v + bo[0];
}

extern "C" void kernel_launch(void* const* d_in, const int* in_sizes, int n_in,
                              void* d_out, int out_size, void* d_ws, size_t ws_size,
                              hipStream_t stream) {
    const int* x = (const int*)d_in[0];
    const int* eidx = (const int*)d_in[1];
    const float* eattr = (const float*)d_in[2];
    const int* batch = (const int*)d_in[3];
    const float* emb = (const float*)d_in[4];
    const float* Wf = (const float*)d_in[5];   // [4][178][64]
    const float* bf = (const float*)d_in[6];   // [4][64]
    const float* Ws = (const float*)d_in[7];
    const float* bs = (const float*)d_in[8];
    const float* W1 = (const float*)d_in[9];   // [64][128]
    const float* b1 = (const float*)d_in[10];
    const float* W2 = (const float*)d_in[11];  // [128][64]
    const float* b2 = (const float*)d_in[12];
    const float* Wo = (const float*)d_in[13];  // [64][1]
    const float* bo = (const float*)d_in[14];
    float* out = (float*)d_out;

    char* p = (char*)d_ws;
    float* h = (float*)p;       p += (size_t)N_NODES * DIM * 4;
    float* dstpack = (float*)p; p += (size_t)N_NODES * 2 * DIM * 4;
    float* srcpack = (float*)p; p += (size_t)N_NODES * 2 * DIM * 4;
    float* agg = (float*)p;     p += (size_t)N_NODES * DIM * 4;
    float* pooled = (float*)p;  p += (size_t)N_GRAPHS * DIM * 4;
    float* counts = (float*)p;  p += (size_t)N_GRAPHS * 4;
    short* wcat = (short*)p;    p += (size_t)NLAYER * 64 * 128 * 2;

    k_embed<<<N_NODES * DIM / 256, 256, 0, stream>>>(x, emb, h);
    k_wcat<<<NLAYER * 64 * 128 / 256, 256, 0, stream>>>(Wf, Ws, wcat);
    for (int l = 0; l < NLAYER; ++l) {
        const float* Wfl = Wf + (size_t)l * ZDIM * DIM;
        const float* Wsl = Ws + (size_t)l * ZDIM * DIM;
        k_nodemm<<<(N_NODES + 63) / 64, 256, 0, stream>>>(
            h, Wfl, bf + l * DIM, Wsl, bs + l * DIM, dstpack, srcpack);
        hipMemsetAsync(agg, 0, (size_t)N_NODES * DIM * 4, stream);
        k_edge<<<2048, 256, 0, stream>>>(eidx, eattr, dstpack, srcpack,
                                         wcat + (size_t)l * 64 * 128, agg);
        k_update<<<N_NODES * DIM / 256, 256, 0, stream>>>(h, agg);
    }
    hipMemsetAsync(pooled, 0, ((size_t)N_GRAPHS * DIM + N_GRAPHS) * 4, stream);
    k_pool<<<N_NODES * DIM / 256, 256, 0, stream>>>(h, batch, pooled, counts);
    k_mlp<<<N_GRAPHS, 64, 0, stream>>>(pooled, counts, W1, b1, W2, b2, Wo, bo, out);
}

// Round 3
// 1345.518 us; speedup vs baseline: 1.7201x; 1.1035x over previous
//
#include <hip/hip_runtime.h>
#include <hip/hip_bf16.h>
#include <math.h>

#define N_NODES 50000
#define N_EDGES 800000
#define N_GRAPHS 256
#define DIM 64
#define EDIM 50
#define HDIM 128
#define NLAYER 4
#define ZDIM (2 * DIM + EDIM)  // 178
#define NTILES (N_EDGES / 32)  // 25000

typedef __attribute__((ext_vector_type(8))) short short8v;
typedef __attribute__((ext_vector_type(16))) float f32x16;

__device__ __forceinline__ float softplus_f(float x) {
    return fmaxf(x, 0.0f) + log1pf(__expf(-fabsf(x)));
}

__device__ __forceinline__ short cvt_bf16(float f) {
    __hip_bfloat16 h = __float2bfloat16(f);
    return *reinterpret_cast<short*>(&h);
}

// h[n][d] = emb[x[n]][d]
__global__ void k_embed(const int* __restrict__ x, const float* __restrict__ emb,
                        float* __restrict__ h) {
    int i = blockIdx.x * 256 + threadIdx.x;  // over N*64 (exact)
    int n = i >> 6, d = i & 63;
    h[i] = emb[x[n] * DIM + d];
}

// Build bf16 edge-weight tiles for all layers:
// wcat[l][k][2*d+g] = (k<50) ? W_g[l][128+k][d] : 0   (k padded to 64)
__global__ void k_wcat(const float* __restrict__ Wf, const float* __restrict__ Ws,
                       short* __restrict__ wcat) {
    int i = blockIdx.x * 256 + threadIdx.x;  // over 4*64*128 = 32768
    int l = i >> 13;
    int rem = i & 8191;
    int k = rem >> 7;
    int colv = rem & 127;
    int d = colv >> 1, g = colv & 1;
    float v = 0.0f;
    if (k < 50) {
        const float* W = g ? Ws : Wf;
        v = W[((size_t)l * ZDIM + 128 + k) * 64 + d];
    }
    wcat[i] = cvt_bf16(v);
}

// Pre-pack eattr into bf16 MFMA A-fragment layout:
// eattrP[((tile*4+kk)*64 + lane)*8 + j] = bf16(eattr[tile*32 + (lane&31)][kk*16 + 8*(lane>>5) + j])
// (zero-padded for k >= 50)
__global__ void k_eprep(const float* __restrict__ eattr, short* __restrict__ eattrP) {
    int i = blockIdx.x * 256 + threadIdx.x;  // over NTILES*4*64 = 6.4M
    int lane = i & 63;
    int kk = (i >> 6) & 3;
    int tile = i >> 8;
    int edge = tile * 32 + (lane & 31);
    int k0 = kk * 16 + 8 * (lane >> 5);
    const float* erow = eattr + (size_t)edge * EDIM;
    short8v v;
#pragma unroll
    for (int j = 0; j < 8; ++j) {
        int k = k0 + j;
        float f = (k < EDIM) ? erow[k] : 0.0f;
        v[j] = cvt_bf16(f);
    }
    *(short8v*)&eattrP[(size_t)i * 8] = v;
}

// Per-layer node-side matmuls (bias folded into dstpack):
__global__ __launch_bounds__(256) void k_nodemm(
    const float* __restrict__ h,
    const float* __restrict__ Wf, const float* __restrict__ bf,
    const float* __restrict__ Ws, const float* __restrict__ bs,
    float* __restrict__ dstpack, float* __restrict__ srcpack) {
    __shared__ float hs[64 * 68];
    int tid = threadIdx.x;
    int w = tid >> 6, d = tid & 63;
    int n0 = blockIdx.x * 64;
    for (int idx = tid; idx < 64 * 64; idx += 256) {
        int i = idx >> 6, k = idx & 63;
        int n = n0 + i;
        hs[i * 68 + k] = (n < N_NODES) ? h[n * DIM + k] : 0.0f;
    }
    __syncthreads();
    const float* Wsel = (w == 0 || w == 2) ? Wf : Ws;
    int row0 = (w < 2) ? 0 : 64;
    float wcol[64];
#pragma unroll
    for (int k = 0; k < 64; ++k) wcol[k] = Wsel[(row0 + k) * 64 + d];
    float bias = (w == 0) ? bf[d] : (w == 1) ? bs[d] : 0.0f;
    float* outp = (w < 2) ? dstpack : srcpack;
    int ch = w & 1;
    int nmax = min(64, N_NODES - n0);
    for (int i = 0; i < nmax; ++i) {
        float acc = bias;
#pragma unroll
        for (int k = 0; k < 64; k += 4) {
            float4 hv = *(const float4*)&hs[i * 68 + k];
            acc += hv.x * wcol[k] + hv.y * wcol[k + 1] + hv.z * wcol[k + 2] + hv.w * wcol[k + 3];
        }
        outp[(size_t)(n0 + i) * 128 + d * 2 + ch] = acc;
    }
}

// Edge kernel (MFMA): per 32-edge tile, 4 waves each compute a 32x32 slice of
// [32 edges] x [128 cols], col = 2*d + gate. K = 64 (eattr padded 50->64).
template <bool PACKED>
__global__ __launch_bounds__(256) void k_edge(
    const int* __restrict__ eidx,       // [2][E]
    const float* __restrict__ eattr,    // [E][50]
    const short* __restrict__ eattrP,   // packed A-fragments (bf16)
    const float* __restrict__ dstpack,  // [N][128]
    const float* __restrict__ srcpack,  // [N][128]
    const short* __restrict__ wcat_l,   // [64][128] bf16
    float* __restrict__ agg) {          // [N][64]
    int tid = threadIdx.x;
    int w = tid >> 6;        // wave 0..3 -> col slice
    int lane = tid & 63;
    int c = lane & 31;       // col within slice / edge row for A
    int h2 = lane >> 5;      // half-wave -> k-offset
    int col = w * 32 + c;

    // B fragments: b[kk][e] = wcat[kk*16 + 8*h2 + e][col]
    short8v bfr[4];
#pragma unroll
    for (int kk = 0; kk < 4; ++kk) {
#pragma unroll
        for (int e = 0; e < 8; ++e) {
            bfr[kk][e] = wcat_l[(kk * 16 + 8 * h2 + e) * 128 + col];
        }
    }

    for (int tile = blockIdx.x; tile < NTILES; tile += gridDim.x) {
        int e0 = tile * 32;

        short8v afr[4];
        if (PACKED) {
#pragma unroll
            for (int kk = 0; kk < 4; ++kk) {
                afr[kk] = *(const short8v*)&eattrP[(((size_t)tile * 4 + kk) * 64 + lane) * 8];
            }
        } else {
            const float* erow = eattr + (size_t)(e0 + c) * EDIM;
#pragma unroll
            for (int kk = 0; kk < 3; ++kk) {
                int k0 = kk * 16 + 8 * h2;
#pragma unroll
                for (int p = 0; p < 4; ++p) {
                    float2 v = *(const float2*)(erow + k0 + 2 * p);
                    afr[kk][2 * p] = cvt_bf16(v.x);
                    afr[kk][2 * p + 1] = cvt_bf16(v.y);
                }
            }
            short8v a;
#pragma unroll
            for (int e = 0; e < 8; ++e) a[e] = 0;
            if (h2 == 0) {
                float2 v = *(const float2*)(erow + 48);
                a[0] = cvt_bf16(v.x);
                a[1] = cvt_bf16(v.y);
            }
            afr[3] = a;
        }

        f32x16 acc;
#pragma unroll
        for (int i = 0; i < 16; ++i) acc[i] = 0.0f;
#pragma unroll
        for (int kk = 0; kk < 4; ++kk) {
            acc = __builtin_amdgcn_mfma_f32_32x32x16_bf16(afr[kk], bfr[kk], acc, 0, 0, 0);
        }

        // Epilogue in 2 groups of 8 rows: batch index loads, batch gathers, then math.
        // C/D layout (32x32): col = lane&31, row = (r&3)+8*(r>>2)+4*h2
#pragma unroll
        for (int grp = 0; grp < 2; ++grp) {
            int tI[8], sI[8];
            float dv[8], sv[8];
#pragma unroll
            for (int r = 0; r < 8; ++r) {
                int rr = grp * 8 + r;
                int row = (rr & 3) + 8 * (rr >> 2) + 4 * h2;
                sI[r] = eidx[e0 + row];
                tI[r] = eidx[N_EDGES + e0 + row];
            }
#pragma unroll
            for (int r = 0; r < 8; ++r) {
                dv[r] = dstpack[(size_t)tI[r] * 128 + col];
                sv[r] = srcpack[(size_t)sI[r] * 128 + col];
            }
#pragma unroll
            for (int r = 0; r < 8; ++r) {
                float pre = acc[grp * 8 + r] + dv[r] + sv[r];
                float e = __expf(-fabsf(pre));
                float q = 1.0f + e;
                float inv = __builtin_amdgcn_rcpf(q);
                float sig = (pre >= 0.0f) ? inv : e * inv;
                float sp = fmaxf(pre, 0.0f) + __logf(q);
                float mine = (c & 1) ? sp : sig;
                float partner = __shfl_xor(mine, 1);
                if (!(c & 1)) {
                    unsafeAtomicAdd(&agg[(size_t)tI[r] * 64 + (col >> 1)], sig * partner);
                }
            }
        }
    }
}

// h = softplus(h + agg); re-zero agg for the next layer
__global__ void k_update(float* __restrict__ h, float* __restrict__ agg) {
    int i = blockIdx.x * 256 + threadIdx.x;
    h[i] = softplus_f(h[i] + agg[i]);
    agg[i] = 0.0f;
}

// pooled[g][d] += h[n][d]; counts[g] += 1
__global__ void k_pool(const float* __restrict__ h, const int* __restrict__ batch,
                       float* __restrict__ pooled, float* __restrict__ counts) {
    int i = blockIdx.x * 256 + threadIdx.x;
    int n = i >> 6, d = i & 63;
    int g = batch[n];
    unsafeAtomicAdd(&pooled[g * DIM + d], h[i]);
    if (d == 0) unsafeAtomicAdd(&counts[g], 1.0f);
}

// out[g] = relu(relu(pooled/cnt @ W1 + b1) @ W2 + b2) @ Wo + bo
__global__ __launch_bounds__(64) void k_mlp(
    const float* __restrict__ pooled, const float* __restrict__ counts,
    const float* __restrict__ W1, const float* __restrict__ b1,
    const float* __restrict__ W2, const float* __restrict__ b2,
    const float* __restrict__ Wo, const float* __restrict__ bo,
    float* __restrict__ out) {
    __shared__ float ps[64];
    __shared__ float h1[128];
    int g = blockIdx.x, lane = threadIdx.x;
    float cnt = fmaxf(counts[g], 1.0f);
    ps[lane] = pooled[g * DIM + lane] / cnt;
    __syncthreads();
#pragma unroll
    for (int rep = 0; rep < 2; ++rep) {
        int j = lane + rep * 64;
        float acc = b1[j];
        for (int k = 0; k < 64; ++k) acc += ps[k] * W1[k * HDIM + j];
        h1[j] = fmaxf(acc, 0.0f);
    }
    __syncthreads();
    float acc = b2[lane];
    for (int k = 0; k < 128; ++k) acc += h1[k] * W2[k * 64 + lane];
    float v = fmaxf(acc, 0.0f) * Wo[lane];
#pragma unroll
    for (int off = 32; off; off >>= 1) v += __shfl_down(v, off);
    if (lane == 0) out[g] = v + bo[0];
}

extern "C" void kernel_launch(void* const* d_in, const int* in_sizes, int n_in,
                              void* d_out, int out_size, void* d_ws, size_t ws_size,
                              hipStream_t stream) {
    const int* x = (const int*)d_in[0];
    const int* eidx = (const int*)d_in[1];
    const float* eattr = (const float*)d_in[2];
    const int* batch = (const int*)d_in[3];
    const float* emb = (const float*)d_in[4];
    const float* Wf = (const float*)d_in[5];   // [4][178][64]
    const float* bf = (const float*)d_in[6];   // [4][64]
    const float* Ws = (const float*)d_in[7];
    const float* bs = (const float*)d_in[8];
    const float* W1 = (const float*)d_in[9];   // [64][128]
    const float* b1 = (const float*)d_in[10];
    const float* W2 = (const float*)d_in[11];  // [128][64]
    const float* b2 = (const float*)d_in[12];
    const float* Wo = (const float*)d_in[13];  // [64][1]
    const float* bo = (const float*)d_in[14];
    float* out = (float*)d_out;

    char* p = (char*)d_ws;
    float* h = (float*)p;       p += (size_t)N_NODES * DIM * 4;
    float* dstpack = (float*)p; p += (size_t)N_NODES * 2 * DIM * 4;
    float* srcpack = (float*)p; p += (size_t)N_NODES * 2 * DIM * 4;
    float* agg = (float*)p;     p += (size_t)N_NODES * DIM * 4;
    float* pooled = (float*)p;  p += (size_t)N_GRAPHS * DIM * 4;
    float* counts = (float*)p;  p += (size_t)N_GRAPHS * 4;
    short* wcat = (short*)p;    p += (size_t)NLAYER * 64 * 128 * 2;
    short* eattrP = (short*)p;  p += (size_t)NTILES * 4 * 64 * 8 * 2;  // 102.4 MB

    bool packed = ((size_t)((char*)p - (char*)d_ws) <= ws_size);

    k_embed<<<N_NODES * DIM / 256, 256, 0, stream>>>(x, emb, h);
    k_wcat<<<NLAYER * 64 * 128 / 256, 256, 0, stream>>>(Wf, Ws, wcat);
    if (packed) {
        k_eprep<<<NTILES, 256, 0, stream>>>(eattr, eattrP);
    }
    hipMemsetAsync(agg, 0, (size_t)N_NODES * DIM * 4, stream);
    for (int l = 0; l < NLAYER; ++l) {
        const float* Wfl = Wf + (size_t)l * ZDIM * DIM;
        const float* Wsl = Ws + (size_t)l * ZDIM * DIM;
        k_nodemm<<<(N_NODES + 63) / 64, 256, 0, stream>>>(
            h, Wfl, bf + l * DIM, Wsl, bs + l * DIM, dstpack, srcpack);
        if (packed) {
            k_edge<true><<<2048, 256, 0, stream>>>(eidx, eattr, eattrP, dstpack, srcpack,
                                                   wcat + (size_t)l * 64 * 128, agg);
        } else {
            k_edge<false><<<2048, 256, 0, stream>>>(eidx, eattr, eattrP, dstpack, srcpack,
                                                    wcat + (size_t)l * 64 * 128, agg);
        }
        k_update<<<N_NODES * DIM / 256, 256, 0, stream>>>(h, agg);
    }
    hipMemsetAsync(pooled, 0, ((size_t)N_GRAPHS * DIM + N_GRAPHS) * 4, stream);
    k_pool<<<N_NODES * DIM / 256, 256, 0, stream>>>(h, batch, pooled, counts);
    k_mlp<<<N_GRAPHS, 64, 0, stream>>>(pooled, counts, W1, b1, W2, b2, Wo, bo, out);
}

// Round 4
// 1270.039 us; speedup vs baseline: 1.8223x; 1.0594x over previous
//
#include <hip/hip_runtime.h>
#include <hip/hip_bf16.h>
#include <math.h>

#define N_NODES 50000
#define N_EDGES 800000
#define N_GRAPHS 256
#define DIM 64
#define EDIM 50
#define HDIM 128
#define NLAYER 4
#define ZDIM (2 * DIM + EDIM)  // 178
#define NTILES (N_EDGES / 32)  // 25000
#define MP 34                  // msgW row pitch (floats)

typedef __attribute__((ext_vector_type(8))) short short8v;
typedef __attribute__((ext_vector_type(16))) float f32x16;

__device__ __forceinline__ float softplus_f(float x) {
    return fmaxf(x, 0.0f) + log1pf(__expf(-fabsf(x)));
}

__device__ __forceinline__ short cvt_bf16(float f) {
    __hip_bfloat16 h = __float2bfloat16(f);
    return *reinterpret_cast<short*>(&h);
}

// h[n][d] = emb[x[n]][d]
__global__ void k_embed(const int* __restrict__ x, const float* __restrict__ emb,
                        float* __restrict__ h) {
    int i = blockIdx.x * 256 + threadIdx.x;
    int n = i >> 6, d = i & 63;
    h[i] = emb[x[n] * DIM + d];
}

// wcat[l][k][2*d+g] = (k<50) ? W_g[l][128+k][d] : 0
__global__ void k_wcat(const float* __restrict__ Wf, const float* __restrict__ Ws,
                       short* __restrict__ wcat) {
    int i = blockIdx.x * 256 + threadIdx.x;  // 4*64*128 = 32768
    int l = i >> 13;
    int rem = i & 8191;
    int k = rem >> 7;
    int colv = rem & 127;
    int d = colv >> 1, g = colv & 1;
    float v = 0.0f;
    if (k < 50) {
        const float* W = g ? Ws : Wf;
        v = W[((size_t)l * ZDIM + 128 + k) * 64 + d];
    }
    wcat[i] = cvt_bf16(v);
}

// ---------------- dst-sort (counting sort) ----------------
__global__ void k_hist(const int* __restrict__ eidx, int* __restrict__ hist) {
    int e = blockIdx.x * 256 + threadIdx.x;  // E exact
    atomicAdd(&hist[eidx[N_EDGES + e]], 1);
}

__global__ __launch_bounds__(256) void k_scan1(const int* __restrict__ hist,
                                               int* __restrict__ scanbuf,
                                               int* __restrict__ blocksums) {
    int tid = threadIdx.x;
    int i = blockIdx.x * 256 + tid;
    int v = (i < N_NODES) ? hist[i] : 0;
    int lane = tid & 63;
#pragma unroll
    for (int off = 1; off < 64; off <<= 1) {
        int u = __shfl_up(v, off);
        if (lane >= off) v += u;
    }
    __shared__ int wsum[4];
    if (lane == 63) wsum[tid >> 6] = v;
    __syncthreads();
    int w = tid >> 6;
    int add = 0;
#pragma unroll
    for (int k = 0; k < 3; ++k)
        if (k < w) add += wsum[k];
    v += add;
    if (i < N_NODES) scanbuf[i] = v;  // block-local inclusive
    if (tid == 255) blocksums[blockIdx.x] = v;
}

__global__ __launch_bounds__(256) void k_scan2(int* __restrict__ blocksums, int nb) {
    int tid = threadIdx.x;
    int v = (tid < nb) ? blocksums[tid] : 0;
    int lane = tid & 63;
#pragma unroll
    for (int off = 1; off < 64; off <<= 1) {
        int u = __shfl_up(v, off);
        if (lane >= off) v += u;
    }
    __shared__ int wsum[4];
    if (lane == 63) wsum[tid >> 6] = v;
    __syncthreads();
    int w = tid >> 6;
    int add = 0;
#pragma unroll
    for (int k = 0; k < 3; ++k)
        if (k < w) add += wsum[k];
    v += add;
    if (tid < nb) blocksums[tid] = v;  // inclusive
}

__global__ void k_scan3(const int* __restrict__ scanbuf, const int* __restrict__ hist,
                        const int* __restrict__ blocksums, int* __restrict__ cursor) {
    int i = blockIdx.x * 256 + threadIdx.x;
    if (i >= N_NODES) return;
    int b = blockIdx.x;
    int off = b ? blocksums[b - 1] : 0;
    cursor[i] = scanbuf[i] - hist[i] + off;  // exclusive start offset
}

__global__ void k_scatter(const int* __restrict__ eidx, int* __restrict__ cursor,
                          int* __restrict__ perm, int* __restrict__ permSrc,
                          int* __restrict__ permDst) {
    int e = blockIdx.x * 256 + threadIdx.x;
    int d = eidx[N_EDGES + e];
    int pos = atomicAdd(&cursor[d], 1);
    perm[pos] = e;
    permDst[pos] = d;
    permSrc[pos] = eidx[e];
}

// Pack eattr (in sorted-edge order if perm != null) into bf16 MFMA A-fragments.
template <bool USE_PERM>
__global__ void k_eprep(const float* __restrict__ eattr, const int* __restrict__ perm,
                        short* __restrict__ eattrP) {
    int i = blockIdx.x * 256 + threadIdx.x;  // NTILES*4*64
    int lane = i & 63;
    int kk = (i >> 6) & 3;
    int tile = i >> 8;
    int pos = tile * 32 + (lane & 31);
    int edge = USE_PERM ? perm[pos] : pos;
    int k0 = kk * 16 + 8 * (lane >> 5);
    const float* erow = eattr + (size_t)edge * EDIM;
    short8v v;
#pragma unroll
    for (int j = 0; j < 8; ++j) {
        int k = k0 + j;
        float f = (k < EDIM) ? erow[k] : 0.0f;
        v[j] = cvt_bf16(f);
    }
    *(short8v*)&eattrP[(size_t)i * 8] = v;
}

// Per-layer node-side matmuls (bias folded into dstpack)
__global__ __launch_bounds__(256) void k_nodemm(
    const float* __restrict__ h,
    const float* __restrict__ Wf, const float* __restrict__ bf,
    const float* __restrict__ Ws, const float* __restrict__ bs,
    float* __restrict__ dstpack, float* __restrict__ srcpack) {
    __shared__ float hs[64 * 68];
    int tid = threadIdx.x;
    int w = tid >> 6, d = tid & 63;
    int n0 = blockIdx.x * 64;
    for (int idx = tid; idx < 64 * 64; idx += 256) {
        int i = idx >> 6, k = idx & 63;
        int n = n0 + i;
        hs[i * 68 + k] = (n < N_NODES) ? h[n * DIM + k] : 0.0f;
    }
    __syncthreads();
    const float* Wsel = (w == 0 || w == 2) ? Wf : Ws;
    int row0 = (w < 2) ? 0 : 64;
    float wcol[64];
#pragma unroll
    for (int k = 0; k < 64; ++k) wcol[k] = Wsel[(row0 + k) * 64 + d];
    float bias = (w == 0) ? bf[d] : (w == 1) ? bs[d] : 0.0f;
    float* outp = (w < 2) ? dstpack : srcpack;
    int ch = w & 1;
    int nmax = min(64, N_NODES - n0);
    for (int i = 0; i < nmax; ++i) {
        float acc = bias;
#pragma unroll
        for (int k = 0; k < 64; k += 4) {
            float4 hv = *(const float4*)&hs[i * 68 + k];
            acc += hv.x * wcol[k] + hv.y * wcol[k + 1] + hv.z * wcol[k + 2] + hv.w * wcol[k + 3];
        }
        outp[(size_t)(n0 + i) * 128 + d * 2 + ch] = acc;
    }
}

// ---------------- sorted edge kernel with LDS segmented reduction ----------------
__global__ __launch_bounds__(256) void k_edge_s(
    const int* __restrict__ permSrc,    // [E] sorted by dst
    const int* __restrict__ permDst,    // [E] sorted (non-decreasing)
    const short* __restrict__ eattrP,   // packed A-fragments (sorted order)
    const float* __restrict__ dstpack,  // [N][128]
    const float* __restrict__ srcpack,  // [N][128]
    const short* __restrict__ wcat_l,   // [64][128] bf16
    float* __restrict__ agg) {          // [N][64]
    __shared__ float msgW[4][32][MP];
    __shared__ int dshI[4][32];
    int tid = threadIdx.x;
    int w = tid >> 6;
    int lane = tid & 63;
    int c = lane & 31;
    int h2 = lane >> 5;
    int col = w * 32 + c;

    short8v bfr[4];
#pragma unroll
    for (int kk = 0; kk < 4; ++kk) {
#pragma unroll
        for (int e = 0; e < 8; ++e) {
            bfr[kk][e] = wcat_l[(kk * 16 + 8 * h2 + e) * 128 + col];
        }
    }

    for (int tile = blockIdx.x; tile < NTILES; tile += gridDim.x) {
        int e0 = tile * 32;

        if (lane < 32) dshI[w][lane] = permDst[e0 + lane];

        short8v afr[4];
#pragma unroll
        for (int kk = 0; kk < 4; ++kk) {
            afr[kk] = *(const short8v*)&eattrP[(((size_t)tile * 4 + kk) * 64 + lane) * 8];
        }

        f32x16 acc;
#pragma unroll
        for (int i = 0; i < 16; ++i) acc[i] = 0.0f;
#pragma unroll
        for (int kk = 0; kk < 4; ++kk) {
            acc = __builtin_amdgcn_mfma_f32_32x32x16_bf16(afr[kk], bfr[kk], acc, 0, 0, 0);
        }

        // Epilogue: compute gate values, write to per-wave LDS tile.
        // C/D layout (32x32): col = lane&31, row = (r&3)+8*(r>>2)+4*h2
#pragma unroll
        for (int grp = 0; grp < 2; ++grp) {
            int tI[8], sI[8];
            float dv[8], sv[8];
#pragma unroll
            for (int r = 0; r < 8; ++r) {
                int rr = grp * 8 + r;
                int row = (rr & 3) + 8 * (rr >> 2) + 4 * h2;
                sI[r] = permSrc[e0 + row];
                tI[r] = permDst[e0 + row];
            }
#pragma unroll
            for (int r = 0; r < 8; ++r) {
                dv[r] = dstpack[(size_t)tI[r] * 128 + col];
                sv[r] = srcpack[(size_t)sI[r] * 128 + col];
            }
#pragma unroll
            for (int r = 0; r < 8; ++r) {
                int rr = grp * 8 + r;
                int row = (rr & 3) + 8 * (rr >> 2) + 4 * h2;
                float pre = acc[rr] + dv[r] + sv[r];
                float e = __expf(-fabsf(pre));
                float q = 1.0f + e;
                float val;
                if (c & 1) {
                    val = fmaxf(pre, 0.0f) + __logf(q);  // softplus
                } else {
                    float inv = __builtin_amdgcn_rcpf(q);
                    val = (pre >= 0.0f) ? inv : e * inv;  // sigmoid
                }
                msgW[w][row][c] = val;
            }
        }

        __builtin_amdgcn_wave_barrier();  // order LDS writes before scan reads (same wave)

        // Segmented scan: lane -> d-offset dd = lane&15, row group (lane>>4)*8..+8
        {
            int dd = lane & 15;
            int base = (lane >> 4) * 8;
            float accum = 0.0f;
            int cur = dshI[w][base];
#pragma unroll
            for (int j = 0; j < 8; ++j) {
                int row = base + j;
                float2 ms = *(const float2*)&msgW[w][row][2 * dd];
                int dn = dshI[w][row];
                if (dn != cur) {
                    unsafeAtomicAdd(&agg[(size_t)cur * 64 + (w * 16 + dd)], accum);
                    accum = 0.0f;
                    cur = dn;
                }
                accum += ms.x * ms.y;  // sigmoid * softplus
            }
            unsafeAtomicAdd(&agg[(size_t)cur * 64 + (w * 16 + dd)], accum);
        }
        __builtin_amdgcn_wave_barrier();
    }
}

// round-3 fallback edge kernel (unsorted, per-element atomics)
template <bool PACKED>
__global__ __launch_bounds__(256) void k_edge(
    const int* __restrict__ eidx, const float* __restrict__ eattr,
    const short* __restrict__ eattrP, const float* __restrict__ dstpack,
    const float* __restrict__ srcpack, const short* __restrict__ wcat_l,
    float* __restrict__ agg) {
    int tid = threadIdx.x;
    int w = tid >> 6;
    int lane = tid & 63;
    int c = lane & 31;
    int h2 = lane >> 5;
    int col = w * 32 + c;
    short8v bfr[4];
#pragma unroll
    for (int kk = 0; kk < 4; ++kk) {
#pragma unroll
        for (int e = 0; e < 8; ++e) bfr[kk][e] = wcat_l[(kk * 16 + 8 * h2 + e) * 128 + col];
    }
    for (int tile = blockIdx.x; tile < NTILES; tile += gridDim.x) {
        int e0 = tile * 32;
        short8v afr[4];
        if (PACKED) {
#pragma unroll
            for (int kk = 0; kk < 4; ++kk)
                afr[kk] = *(const short8v*)&eattrP[(((size_t)tile * 4 + kk) * 64 + lane) * 8];
        } else {
            const float* erow = eattr + (size_t)(e0 + c) * EDIM;
#pragma unroll
            for (int kk = 0; kk < 3; ++kk) {
                int k0 = kk * 16 + 8 * h2;
#pragma unroll
                for (int p = 0; p < 4; ++p) {
                    float2 v = *(const float2*)(erow + k0 + 2 * p);
                    afr[kk][2 * p] = cvt_bf16(v.x);
                    afr[kk][2 * p + 1] = cvt_bf16(v.y);
                }
            }
            short8v a;
#pragma unroll
            for (int e = 0; e < 8; ++e) a[e] = 0;
            if (h2 == 0) {
                float2 v = *(const float2*)(erow + 48);
                a[0] = cvt_bf16(v.x);
                a[1] = cvt_bf16(v.y);
            }
            afr[3] = a;
        }
        f32x16 acc;
#pragma unroll
        for (int i = 0; i < 16; ++i) acc[i] = 0.0f;
#pragma unroll
        for (int kk = 0; kk < 4; ++kk)
            acc = __builtin_amdgcn_mfma_f32_32x32x16_bf16(afr[kk], bfr[kk], acc, 0, 0, 0);
#pragma unroll
        for (int grp = 0; grp < 2; ++grp) {
            int tI[8], sI[8];
            float dv[8], sv[8];
#pragma unroll
            for (int r = 0; r < 8; ++r) {
                int rr = grp * 8 + r;
                int row = (rr & 3) + 8 * (rr >> 2) + 4 * h2;
                sI[r] = eidx[e0 + row];
                tI[r] = eidx[N_EDGES + e0 + row];
            }
#pragma unroll
            for (int r = 0; r < 8; ++r) {
                dv[r] = dstpack[(size_t)tI[r] * 128 + col];
                sv[r] = srcpack[(size_t)sI[r] * 128 + col];
            }
#pragma unroll
            for (int r = 0; r < 8; ++r) {
                float pre = acc[grp * 8 + r] + dv[r] + sv[r];
                float e = __expf(-fabsf(pre));
                float q = 1.0f + e;
                float inv = __builtin_amdgcn_rcpf(q);
                float sig = (pre >= 0.0f) ? inv : e * inv;
                float sp = fmaxf(pre, 0.0f) + __logf(q);
                float mine = (c & 1) ? sp : sig;
                float partner = __shfl_xor(mine, 1);
                if (!(c & 1)) unsafeAtomicAdd(&agg[(size_t)tI[r] * 64 + (col >> 1)], sig * partner);
            }
        }
    }
}

// h = softplus(h + agg); re-zero agg for the next layer
__global__ void k_update(float* __restrict__ h, float* __restrict__ agg) {
    int i = blockIdx.x * 256 + threadIdx.x;
    h[i] = softplus_f(h[i] + agg[i]);
    agg[i] = 0.0f;
}

__global__ void k_pool(const float* __restrict__ h, const int* __restrict__ batch,
                       float* __restrict__ pooled, float* __restrict__ counts) {
    int i = blockIdx.x * 256 + threadIdx.x;
    int n = i >> 6, d = i & 63;
    int g = batch[n];
    unsafeAtomicAdd(&pooled[g * DIM + d], h[i]);
    if (d == 0) unsafeAtomicAdd(&counts[g], 1.0f);
}

__global__ __launch_bounds__(64) void k_mlp(
    const float* __restrict__ pooled, const float* __restrict__ counts,
    const float* __restrict__ W1, const float* __restrict__ b1,
    const float* __restrict__ W2, const float* __restrict__ b2,
    const float* __restrict__ Wo, const float* __restrict__ bo,
    float* __restrict__ out) {
    __shared__ float ps[64];
    __shared__ float h1[128];
    int g = blockIdx.x, lane = threadIdx.x;
    float cnt = fmaxf(counts[g], 1.0f);
    ps[lane] = pooled[g * DIM + lane] / cnt;
    __syncthreads();
#pragma unroll
    for (int rep = 0; rep < 2; ++rep) {
        int j = lane + rep * 64;
        float acc = b1[j];
        for (int k = 0; k < 64; ++k) acc += ps[k] * W1[k * HDIM + j];
        h1[j] = fmaxf(acc, 0.0f);
    }
    __syncthreads();
    float acc = b2[lane];
    for (int k = 0; k < 128; ++k) acc += h1[k] * W2[k * 64 + lane];
    float v = fmaxf(acc, 0.0f) * Wo[lane];
#pragma unroll
    for (int off = 32; off; off >>= 1) v += __shfl_down(v, off);
    if (lane == 0) out[g] = v + bo[0];
}

extern "C" void kernel_launch(void* const* d_in, const int* in_sizes, int n_in,
                              void* d_out, int out_size, void* d_ws, size_t ws_size,
                              hipStream_t stream) {
    const int* x = (const int*)d_in[0];
    const int* eidx = (const int*)d_in[1];
    const float* eattr = (const float*)d_in[2];
    const int* batch = (const int*)d_in[3];
    const float* emb = (const float*)d_in[4];
    const float* Wf = (const float*)d_in[5];
    const float* bf = (const float*)d_in[6];
    const float* Ws = (const float*)d_in[7];
    const float* bs = (const float*)d_in[8];
    const float* W1 = (const float*)d_in[9];
    const float* b1 = (const float*)d_in[10];
    const float* W2 = (const float*)d_in[11];
    const float* b2 = (const float*)d_in[12];
    const float* Wo = (const float*)d_in[13];
    const float* bo = (const float*)d_in[14];
    float* out = (float*)d_out;

    char* p = (char*)d_ws;
    float* h = (float*)p;       p += (size_t)N_NODES * DIM * 4;
    float* dstpack = (float*)p; p += (size_t)N_NODES * 2 * DIM * 4;
    float* srcpack = (float*)p; p += (size_t)N_NODES * 2 * DIM * 4;
    float* agg = (float*)p;     p += (size_t)N_NODES * DIM * 4;
    float* pooled = (float*)p;  p += (size_t)N_GRAPHS * DIM * 4;
    float* counts = (float*)p;  p += (size_t)N_GRAPHS * 4;
    short* wcat = (short*)p;    p += (size_t)NLAYER * 64 * 128 * 2;
    short* eattrP = (short*)p;  p += (size_t)NTILES * 4 * 64 * 8 * 2;  // 102.4 MB
    size_t used_packed = (size_t)(p - (char*)d_ws);
    int* hist = (int*)p;        p += (size_t)N_NODES * 4;
    int* scanbuf = (int*)p;     p += (size_t)N_NODES * 4;
    int* blocksums = (int*)p;   p += 256 * 4;
    int* cursor = (int*)p;      p += (size_t)N_NODES * 4;
    int* perm = (int*)p;        p += (size_t)N_EDGES * 4;
    int* permSrc = (int*)p;     p += (size_t)N_EDGES * 4;
    int* permDst = (int*)p;     p += (size_t)N_EDGES * 4;
    size_t used_sorted = (size_t)(p - (char*)d_ws);

    bool packed = used_packed <= ws_size;
    bool sorted = used_sorted <= ws_size;

    const int SCAN_BLOCKS = (N_NODES + 255) / 256;  // 196

    k_embed<<<N_NODES * DIM / 256, 256, 0, stream>>>(x, emb, h);
    k_wcat<<<NLAYER * 64 * 128 / 256, 256, 0, stream>>>(Wf, Ws, wcat);
    if (sorted) {
        hipMemsetAsync(hist, 0, (size_t)N_NODES * 4, stream);
        k_hist<<<N_EDGES / 256, 256, 0, stream>>>(eidx, hist);
        k_scan1<<<SCAN_BLOCKS, 256, 0, stream>>>(hist, scanbuf, blocksums);
        k_scan2<<<1, 256, 0, stream>>>(blocksums, SCAN_BLOCKS);
        k_scan3<<<SCAN_BLOCKS, 256, 0, stream>>>(scanbuf, hist, blocksums, cursor);
        k_scatter<<<N_EDGES / 256, 256, 0, stream>>>(eidx, cursor, perm, permSrc, permDst);
        k_eprep<true><<<NTILES, 256, 0, stream>>>(eattr, perm, eattrP);
    } else if (packed) {
        k_eprep<false><<<NTILES, 256, 0, stream>>>(eattr, nullptr, eattrP);
    }
    hipMemsetAsync(agg, 0, (size_t)N_NODES * DIM * 4, stream);
    for (int l = 0; l < NLAYER; ++l) {
        const float* Wfl = Wf + (size_t)l * ZDIM * DIM;
        const float* Wsl = Ws + (size_t)l * ZDIM * DIM;
        k_nodemm<<<(N_NODES + 63) / 64, 256, 0, stream>>>(
            h, Wfl, bf + l * DIM, Wsl, bs + l * DIM, dstpack, srcpack);
        if (sorted) {
            k_edge_s<<<2048, 256, 0, stream>>>(permSrc, permDst, eattrP, dstpack, srcpack,
                                               wcat + (size_t)l * 64 * 128, agg);
        } else if (packed) {
            k_edge<true><<<2048, 256, 0, stream>>>(eidx, eattr, eattrP, dstpack, srcpack,
                                                   wcat + (size_t)l * 64 * 128, agg);
        } else {
            k_edge<false><<<2048, 256, 0, stream>>>(eidx, eattr, eattrP, dstpack, srcpack,
                                                    wcat + (size_t)l * 64 * 128, agg);
        }
        k_update<<<N_NODES * DIM / 256, 256, 0, stream>>>(h, agg);
    }
    hipMemsetAsync(pooled, 0, ((size_t)N_GRAPHS * DIM + N_GRAPHS) * 4, stream);
    k_pool<<<N_NODES * DIM / 256, 256, 0, stream>>>(h, batch, pooled, counts);
    k_mlp<<<N_GRAPHS, 64, 0, stream>>>(pooled, counts, W1, b1, W2, b2, Wo, bo, out);
}

// Round 5
// 1193.151 us; speedup vs baseline: 1.9398x; 1.0644x over previous
//
#include <hip/hip_runtime.h>
#include <hip/hip_bf16.h>
#include <math.h>

#define N_NODES 50000
#define N_EDGES 800000
#define N_GRAPHS 256
#define DIM 64
#define EDIM 50
#define HDIM 128
#define NLAYER 4
#define ZDIM (2 * DIM + EDIM)  // 178
#define NTILES (N_EDGES / 32)  // 25000
#define MP 34                  // msgW row pitch (floats)

typedef __attribute__((ext_vector_type(8))) short short8v;
typedef __attribute__((ext_vector_type(16))) float f32x16;

__device__ __forceinline__ float softplus_f(float x) {
    return fmaxf(x, 0.0f) + log1pf(__expf(-fabsf(x)));
}

__device__ __forceinline__ short cvt_bf16(float f) {
    __hip_bfloat16 h = __float2bfloat16(f);
    return *reinterpret_cast<short*>(&h);
}

// h[n][d] = emb[x[n]][d]
__global__ void k_embed(const int* __restrict__ x, const float* __restrict__ emb,
                        float* __restrict__ h) {
    int i = blockIdx.x * 256 + threadIdx.x;
    int n = i >> 6, d = i & 63;
    h[i] = emb[x[n] * DIM + d];
}

// wcat[l][k][2*d+g] = (k<50) ? W_g[l][128+k][d] : 0
__global__ void k_wcat(const float* __restrict__ Wf, const float* __restrict__ Ws,
                       short* __restrict__ wcat) {
    int i = blockIdx.x * 256 + threadIdx.x;  // 4*64*128 = 32768
    int l = i >> 13;
    int rem = i & 8191;
    int k = rem >> 7;
    int colv = rem & 127;
    int d = colv >> 1, g = colv & 1;
    float v = 0.0f;
    if (k < 50) {
        const float* W = g ? Ws : Wf;
        v = W[((size_t)l * ZDIM + 128 + k) * 64 + d];
    }
    wcat[i] = cvt_bf16(v);
}

// ---------------- dst-sort (counting sort) ----------------
__global__ void k_hist(const int* __restrict__ eidx, int* __restrict__ hist) {
    int e = blockIdx.x * 256 + threadIdx.x;  // E exact
    atomicAdd(&hist[eidx[N_EDGES + e]], 1);
}

__global__ __launch_bounds__(256) void k_scan1(const int* __restrict__ hist,
                                               int* __restrict__ scanbuf,
                                               int* __restrict__ blocksums) {
    int tid = threadIdx.x;
    int i = blockIdx.x * 256 + tid;
    int v = (i < N_NODES) ? hist[i] : 0;
    int lane = tid & 63;
#pragma unroll
    for (int off = 1; off < 64; off <<= 1) {
        int u = __shfl_up(v, off);
        if (lane >= off) v += u;
    }
    __shared__ int wsum[4];
    if (lane == 63) wsum[tid >> 6] = v;
    __syncthreads();
    int w = tid >> 6;
    int add = 0;
#pragma unroll
    for (int k = 0; k < 3; ++k)
        if (k < w) add += wsum[k];
    v += add;
    if (i < N_NODES) scanbuf[i] = v;
    if (tid == 255) blocksums[blockIdx.x] = v;
}

__global__ __launch_bounds__(256) void k_scan2(int* __restrict__ blocksums, int nb) {
    int tid = threadIdx.x;
    int v = (tid < nb) ? blocksums[tid] : 0;
    int lane = tid & 63;
#pragma unroll
    for (int off = 1; off < 64; off <<= 1) {
        int u = __shfl_up(v, off);
        if (lane >= off) v += u;
    }
    __shared__ int wsum[4];
    if (lane == 63) wsum[tid >> 6] = v;
    __syncthreads();
    int w = tid >> 6;
    int add = 0;
#pragma unroll
    for (int k = 0; k < 3; ++k)
        if (k < w) add += wsum[k];
    v += add;
    if (tid < nb) blocksums[tid] = v;
}

__global__ void k_scan3(const int* __restrict__ scanbuf, const int* __restrict__ hist,
                        const int* __restrict__ blocksums, int* __restrict__ cursor) {
    int i = blockIdx.x * 256 + threadIdx.x;
    if (i >= N_NODES) return;
    int b = blockIdx.x;
    int off = b ? blocksums[b - 1] : 0;
    cursor[i] = scanbuf[i] - hist[i] + off;
}

__global__ void k_scatter(const int* __restrict__ eidx, int* __restrict__ cursor,
                          int* __restrict__ perm, int* __restrict__ permSrc,
                          int* __restrict__ permDst) {
    int e = blockIdx.x * 256 + threadIdx.x;
    int d = eidx[N_EDGES + e];
    int pos = atomicAdd(&cursor[d], 1);
    perm[pos] = e;
    permDst[pos] = d;
    permSrc[pos] = eidx[e];
}

// Fast sorted pack: thread = (tile, lane); handles all 4 kk fragments.
// 13 independent 8B-aligned float2 loads, then cvt, then 4 coalesced 16B stores.
__global__ __launch_bounds__(256) void k_eprep2(const float* __restrict__ eattr,
                                                const int* __restrict__ perm,
                                                short* __restrict__ eattrP) {
    int i = blockIdx.x * 256 + threadIdx.x;  // over NTILES*64 = 1.6M
    int lane = i & 63;
    int tile = i >> 6;
    int pos = tile * 32 + (lane & 31);
    int h2 = lane >> 5;
    int edge = perm[pos];
    const float* erow = eattr + (size_t)edge * EDIM;  // byte base 200*edge: 8B-aligned
    int k0 = 8 * h2;
    float2 v[12];
#pragma unroll
    for (int kk = 0; kk < 3; ++kk) {
#pragma unroll
        for (int p = 0; p < 4; ++p) {
            v[kk * 4 + p] = *(const float2*)(erow + k0 + 16 * kk + 2 * p);
        }
    }
    float2 t48 = make_float2(0.0f, 0.0f);
    if (h2 == 0) t48 = *(const float2*)(erow + 48);

    size_t fb = ((size_t)tile * 4) * 64 + lane;  // fragment slot for kk=0
#pragma unroll
    for (int kk = 0; kk < 3; ++kk) {
        short8v o;
#pragma unroll
        for (int p = 0; p < 4; ++p) {
            o[2 * p] = cvt_bf16(v[kk * 4 + p].x);
            o[2 * p + 1] = cvt_bf16(v[kk * 4 + p].y);
        }
        *(short8v*)&eattrP[(fb + (size_t)kk * 64) * 8] = o;
    }
    short8v o;
#pragma unroll
    for (int e = 0; e < 8; ++e) o[e] = 0;
    o[0] = cvt_bf16(t48.x);
    o[1] = cvt_bf16(t48.y);
    *(short8v*)&eattrP[(fb + 3 * 64) * 8] = o;
}

// fallback pack (natural order), only used if ws too small for sort
__global__ void k_eprep(const float* __restrict__ eattr, short* __restrict__ eattrP) {
    int i = blockIdx.x * 256 + threadIdx.x;
    int lane = i & 63;
    int kk = (i >> 6) & 3;
    int tile = i >> 8;
    int edge = tile * 32 + (lane & 31);
    int k0 = kk * 16 + 8 * (lane >> 5);
    const float* erow = eattr + (size_t)edge * EDIM;
    short8v v;
#pragma unroll
    for (int j = 0; j < 8; ++j) {
        int k = k0 + j;
        float f = (k < EDIM) ? erow[k] : 0.0f;
        v[j] = cvt_bf16(f);
    }
    *(short8v*)&eattrP[(size_t)i * 8] = v;
}

// Per-layer node-side matmuls (bias folded into dstpack).
// Lane mapping: colv = (w&1)*64 + lane -> contiguous 256B wave stores.
__global__ __launch_bounds__(256) void k_nodemm(
    const float* __restrict__ h,
    const float* __restrict__ Wf, const float* __restrict__ bf,
    const float* __restrict__ Ws, const float* __restrict__ bs,
    float* __restrict__ dstpack, float* __restrict__ srcpack) {
    __shared__ float hs[64 * 68];
    int tid = threadIdx.x;
    int w = tid >> 6, lane = tid & 63;
    int n0 = blockIdx.x * 64;
    for (int idx = tid; idx < 64 * 64; idx += 256) {
        int i = idx >> 6, k = idx & 63;
        int n = n0 + i;
        hs[i * 68 + k] = (n < N_NODES) ? h[n * DIM + k] : 0.0f;
    }
    __syncthreads();
    int colv = (w & 1) * 64 + lane;  // 0..127
    int d = colv >> 1, g = colv & 1;
    const float* Wsel = g ? Ws : Wf;
    int row0 = (w < 2) ? 0 : 64;
    float wcol[64];
#pragma unroll
    for (int k = 0; k < 64; ++k) wcol[k] = Wsel[(row0 + k) * 64 + d];
    float bias = (w < 2) ? (g ? bs[d] : bf[d]) : 0.0f;
    float* outp = (w < 2) ? dstpack : srcpack;
    int nmax = min(64, N_NODES - n0);
    for (int i = 0; i < nmax; ++i) {
        float acc = bias;
#pragma unroll
        for (int k = 0; k < 64; k += 4) {
            float4 hv = *(const float4*)&hs[i * 68 + k];
            acc += hv.x * wcol[k] + hv.y * wcol[k + 1] + hv.z * wcol[k + 2] + hv.w * wcol[k + 3];
        }
        outp[(size_t)(n0 + i) * 128 + colv] = acc;
    }
}

// ---------------- sorted edge kernel with LDS segmented reduction ----------------
__global__ __launch_bounds__(256) void k_edge_s(
    const int* __restrict__ permSrc,    // [E] sorted by dst
    const int* __restrict__ permDst,    // [E] sorted (non-decreasing)
    const short* __restrict__ eattrP,   // packed A-fragments (sorted order)
    const float* __restrict__ dstpack,  // [N][128]
    const float* __restrict__ srcpack,  // [N][128]
    const short* __restrict__ wcat_l,   // [64][128] bf16
    float* __restrict__ agg) {          // [N][64]
    __shared__ float msgW[4][32][MP];
    __shared__ int dshI[4][32];
    int tid = threadIdx.x;
    int w = tid >> 6;
    int lane = tid & 63;
    int c = lane & 31;
    int h2 = lane >> 5;
    int col = w * 32 + c;

    short8v bfr[4];
#pragma unroll
    for (int kk = 0; kk < 4; ++kk) {
#pragma unroll
        for (int e = 0; e < 8; ++e) {
            bfr[kk][e] = wcat_l[(kk * 16 + 8 * h2 + e) * 128 + col];
        }
    }

    for (int tile = blockIdx.x; tile < NTILES; tile += gridDim.x) {
        int e0 = tile * 32;

        if (lane < 32) dshI[w][lane] = permDst[e0 + lane];

        short8v afr[4];
#pragma unroll
        for (int kk = 0; kk < 4; ++kk) {
            afr[kk] = *(const short8v*)&eattrP[(((size_t)tile * 4 + kk) * 64 + lane) * 8];
        }

        f32x16 acc;
#pragma unroll
        for (int i = 0; i < 16; ++i) acc[i] = 0.0f;
#pragma unroll
        for (int kk = 0; kk < 4; ++kk) {
            acc = __builtin_amdgcn_mfma_f32_32x32x16_bf16(afr[kk], bfr[kk], acc, 0, 0, 0);
        }

#pragma unroll
        for (int grp = 0; grp < 2; ++grp) {
            int tI[8], sI[8];
            float dv[8], sv[8];
#pragma unroll
            for (int r = 0; r < 8; ++r) {
                int rr = grp * 8 + r;
                int row = (rr & 3) + 8 * (rr >> 2) + 4 * h2;
                sI[r] = permSrc[e0 + row];
                tI[r] = permDst[e0 + row];
            }
#pragma unroll
            for (int r = 0; r < 8; ++r) {
                dv[r] = dstpack[(size_t)tI[r] * 128 + col];
                sv[r] = srcpack[(size_t)sI[r] * 128 + col];
            }
#pragma unroll
            for (int r = 0; r < 8; ++r) {
                int rr = grp * 8 + r;
                int row = (rr & 3) + 8 * (rr >> 2) + 4 * h2;
                float pre = acc[rr] + dv[r] + sv[r];
                float e = __expf(-fabsf(pre));
                float q = 1.0f + e;
                float val;
                if (c & 1) {
                    val = fmaxf(pre, 0.0f) + __logf(q);  // softplus
                } else {
                    float inv = __builtin_amdgcn_rcpf(q);
                    val = (pre >= 0.0f) ? inv : e * inv;  // sigmoid
                }
                msgW[w][row][c] = val;
            }
        }

        __builtin_amdgcn_wave_barrier();

        {
            int dd = lane & 15;
            int base = (lane >> 4) * 8;
            float accum = 0.0f;
            int cur = dshI[w][base];
#pragma unroll
            for (int j = 0; j < 8; ++j) {
                int row = base + j;
                float2 ms = *(const float2*)&msgW[w][row][2 * dd];
                int dn = dshI[w][row];
                if (dn != cur) {
                    unsafeAtomicAdd(&agg[(size_t)cur * 64 + (w * 16 + dd)], accum);
                    accum = 0.0f;
                    cur = dn;
                }
                accum += ms.x * ms.y;
            }
            unsafeAtomicAdd(&agg[(size_t)cur * 64 + (w * 16 + dd)], accum);
        }
        __builtin_amdgcn_wave_barrier();
    }
}

// fallback edge kernel (unsorted, per-element atomics)
template <bool PACKED>
__global__ __launch_bounds__(256) void k_edge(
    const int* __restrict__ eidx, const float* __restrict__ eattr,
    const short* __restrict__ eattrP, const float* __restrict__ dstpack,
    const float* __restrict__ srcpack, const short* __restrict__ wcat_l,
    float* __restrict__ agg) {
    int tid = threadIdx.x;
    int w = tid >> 6;
    int lane = tid & 63;
    int c = lane & 31;
    int h2 = lane >> 5;
    int col = w * 32 + c;
    short8v bfr[4];
#pragma unroll
    for (int kk = 0; kk < 4; ++kk) {
#pragma unroll
        for (int e = 0; e < 8; ++e) bfr[kk][e] = wcat_l[(kk * 16 + 8 * h2 + e) * 128 + col];
    }
    for (int tile = blockIdx.x; tile < NTILES; tile += gridDim.x) {
        int e0 = tile * 32;
        short8v afr[4];
        if (PACKED) {
#pragma unroll
            for (int kk = 0; kk < 4; ++kk)
                afr[kk] = *(const short8v*)&eattrP[(((size_t)tile * 4 + kk) * 64 + lane) * 8];
        } else {
            const float* erow = eattr + (size_t)(e0 + c) * EDIM;
#pragma unroll
            for (int kk = 0; kk < 3; ++kk) {
                int k0 = kk * 16 + 8 * h2;
#pragma unroll
                for (int p = 0; p < 4; ++p) {
                    float2 v = *(const float2*)(erow + k0 + 2 * p);
                    afr[kk][2 * p] = cvt_bf16(v.x);
                    afr[kk][2 * p + 1] = cvt_bf16(v.y);
                }
            }
            short8v a;
#pragma unroll
            for (int e = 0; e < 8; ++e) a[e] = 0;
            if (h2 == 0) {
                float2 v = *(const float2*)(erow + 48);
                a[0] = cvt_bf16(v.x);
                a[1] = cvt_bf16(v.y);
            }
            afr[3] = a;
        }
        f32x16 acc;
#pragma unroll
        for (int i = 0; i < 16; ++i) acc[i] = 0.0f;
#pragma unroll
        for (int kk = 0; kk < 4; ++kk)
            acc = __builtin_amdgcn_mfma_f32_32x32x16_bf16(afr[kk], bfr[kk], acc, 0, 0, 0);
#pragma unroll
        for (int grp = 0; grp < 2; ++grp) {
            int tI[8], sI[8];
            float dv[8], sv[8];
#pragma unroll
            for (int r = 0; r < 8; ++r) {
                int rr = grp * 8 + r;
                int row = (rr & 3) + 8 * (rr >> 2) + 4 * h2;
                sI[r] = eidx[e0 + row];
                tI[r] = eidx[N_EDGES + e0 + row];
            }
#pragma unroll
            for (int r = 0; r < 8; ++r) {
                dv[r] = dstpack[(size_t)tI[r] * 128 + col];
                sv[r] = srcpack[(size_t)sI[r] * 128 + col];
            }
#pragma unroll
            for (int r = 0; r < 8; ++r) {
                float pre = acc[grp * 8 + r] + dv[r] + sv[r];
                float e = __expf(-fabsf(pre));
                float q = 1.0f + e;
                float inv = __builtin_amdgcn_rcpf(q);
                float sig = (pre >= 0.0f) ? inv : e * inv;
                float sp = fmaxf(pre, 0.0f) + __logf(q);
                float mine = (c & 1) ? sp : sig;
                float partner = __shfl_xor(mine, 1);
                if (!(c & 1)) unsafeAtomicAdd(&agg[(size_t)tI[r] * 64 + (col >> 1)], sig * partner);
            }
        }
    }
}

// h = softplus(h + agg); re-zero agg for the next layer
__global__ void k_update(float* __restrict__ h, float* __restrict__ agg) {
    int i = blockIdx.x * 256 + threadIdx.x;
    h[i] = softplus_f(h[i] + agg[i]);
    agg[i] = 0.0f;
}

__global__ void k_pool(const float* __restrict__ h, const int* __restrict__ batch,
                       float* __restrict__ pooled, float* __restrict__ counts) {
    int i = blockIdx.x * 256 + threadIdx.x;
    int n = i >> 6, d = i & 63;
    int g = batch[n];
    unsafeAtomicAdd(&pooled[g * DIM + d], h[i]);
    if (d == 0) unsafeAtomicAdd(&counts[g], 1.0f);
}

__global__ __launch_bounds__(64) void k_mlp(
    const float* __restrict__ pooled, const float* __restrict__ counts,
    const float* __restrict__ W1, const float* __restrict__ b1,
    const float* __restrict__ W2, const float* __restrict__ b2,
    const float* __restrict__ Wo, const float* __restrict__ bo,
    float* __restrict__ out) {
    __shared__ float ps[64];
    __shared__ float h1[128];
    int g = blockIdx.x, lane = threadIdx.x;
    float cnt = fmaxf(counts[g], 1.0f);
    ps[lane] = pooled[g * DIM + lane] / cnt;
    __syncthreads();
#pragma unroll
    for (int rep = 0; rep < 2; ++rep) {
        int j = lane + rep * 64;
        float acc = b1[j];
        for (int k = 0; k < 64; ++k) acc += ps[k] * W1[k * HDIM + j];
        h1[j] = fmaxf(acc, 0.0f);
    }
    __syncthreads();
    float acc = b2[lane];
    for (int k = 0; k < 128; ++k) acc += h1[k] * W2[k * 64 + lane];
    float v = fmaxf(acc, 0.0f) * Wo[lane];
#pragma unroll
    for (int off = 32; off; off >>= 1) v += __shfl_down(v, off);
    if (lane == 0) out[g] = v + bo[0];
}

extern "C" void kernel_launch(void* const* d_in, const int* in_sizes, int n_in,
                              void* d_out, int out_size, void* d_ws, size_t ws_size,
                              hipStream_t stream) {
    const int* x = (const int*)d_in[0];
    const int* eidx = (const int*)d_in[1];
    const float* eattr = (const float*)d_in[2];
    const int* batch = (const int*)d_in[3];
    const float* emb = (const float*)d_in[4];
    const float* Wf = (const float*)d_in[5];
    const float* bf = (const float*)d_in[6];
    const float* Ws = (const float*)d_in[7];
    const float* bs = (const float*)d_in[8];
    const float* W1 = (const float*)d_in[9];
    const float* b1 = (const float*)d_in[10];
    const float* W2 = (const float*)d_in[11];
    const float* b2 = (const float*)d_in[12];
    const float* Wo = (const float*)d_in[13];
    const float* bo = (const float*)d_in[14];
    float* out = (float*)d_out;

    char* p = (char*)d_ws;
    float* h = (float*)p;       p += (size_t)N_NODES * DIM * 4;
    float* dstpack = (float*)p; p += (size_t)N_NODES * 2 * DIM * 4;
    float* srcpack = (float*)p; p += (size_t)N_NODES * 2 * DIM * 4;
    float* agg = (float*)p;     p += (size_t)N_NODES * DIM * 4;
    float* pooled = (float*)p;  p += (size_t)N_GRAPHS * DIM * 4;
    float* counts = (float*)p;  p += (size_t)N_GRAPHS * 4;
    short* wcat = (short*)p;    p += (size_t)NLAYER * 64 * 128 * 2;
    short* eattrP = (short*)p;  p += (size_t)NTILES * 4 * 64 * 8 * 2;  // 102.4 MB
    size_t used_packed = (size_t)(p - (char*)d_ws);
    int* hist = (int*)p;        p += (size_t)N_NODES * 4;
    int* scanbuf = (int*)p;     p += (size_t)N_NODES * 4;
    int* blocksums = (int*)p;   p += 256 * 4;
    int* cursor = (int*)p;      p += (size_t)N_NODES * 4;
    int* perm = (int*)p;        p += (size_t)N_EDGES * 4;
    int* permSrc = (int*)p;     p += (size_t)N_EDGES * 4;
    int* permDst = (int*)p;     p += (size_t)N_EDGES * 4;
    size_t used_sorted = (size_t)(p - (char*)d_ws);

    bool packed = used_packed <= ws_size;
    bool sorted = used_sorted <= ws_size;

    const int SCAN_BLOCKS = (N_NODES + 255) / 256;  // 196

    k_embed<<<N_NODES * DIM / 256, 256, 0, stream>>>(x, emb, h);
    k_wcat<<<NLAYER * 64 * 128 / 256, 256, 0, stream>>>(Wf, Ws, wcat);
    if (sorted) {
        hipMemsetAsync(hist, 0, (size_t)N_NODES * 4, stream);
        k_hist<<<N_EDGES / 256, 256, 0, stream>>>(eidx, hist);
        k_scan1<<<SCAN_BLOCKS, 256, 0, stream>>>(hist, scanbuf, blocksums);
        k_scan2<<<1, 256, 0, stream>>>(blocksums, SCAN_BLOCKS);
        k_scan3<<<SCAN_BLOCKS, 256, 0, stream>>>(scanbuf, hist, blocksums, cursor);
        k_scatter<<<N_EDGES / 256, 256, 0, stream>>>(eidx, cursor, perm, permSrc, permDst);
        k_eprep2<<<NTILES * 64 / 256, 256, 0, stream>>>(eattr, perm, eattrP);
    } else if (packed) {
        k_eprep<<<NTILES, 256, 0, stream>>>(eattr, eattrP);
    }
    hipMemsetAsync(agg, 0, (size_t)N_NODES * DIM * 4, stream);
    for (int l = 0; l < NLAYER; ++l) {
        const float* Wfl = Wf + (size_t)l * ZDIM * DIM;
        const float* Wsl = Ws + (size_t)l * ZDIM * DIM;
        k_nodemm<<<(N_NODES + 63) / 64, 256, 0, stream>>>(
            h, Wfl, bf + l * DIM, Wsl, bs + l * DIM, dstpack, srcpack);
        if (sorted) {
            k_edge_s<<<2048, 256, 0, stream>>>(permSrc, permDst, eattrP, dstpack, srcpack,
                                               wcat + (size_t)l * 64 * 128, agg);
        } else if (packed) {
            k_edge<true><<<2048, 256, 0, stream>>>(eidx, eattr, eattrP, dstpack, srcpack,
                                                   wcat + (size_t)l * 64 * 128, agg);
        } else {
            k_edge<false><<<2048, 256, 0, stream>>>(eidx, eattr, eattrP, dstpack, srcpack,
                                                    wcat + (size_t)l * 64 * 128, agg);
        }
        k_update<<<N_NODES * DIM / 256, 256, 0, stream>>>(h, agg);
    }
    hipMemsetAsync(pooled, 0, ((size_t)N_GRAPHS * DIM + N_GRAPHS) * 4, stream);
    k_pool<<<N_NODES * DIM / 256, 256, 0, stream>>>(h, batch, pooled, counts);
    k_mlp<<<N_GRAPHS, 64, 0, stream>>>(pooled, counts, W1, b1, W2, b2, Wo, bo, out);
}

// Round 6
// 1072.152 us; speedup vs baseline: 2.1587x; 1.1129x over previous
//
#include <hip/hip_runtime.h>
#include <hip/hip_bf16.h>
#include <math.h>

#define N_NODES 50000
#define N_EDGES 800000
#define N_GRAPHS 256
#define DIM 64
#define EDIM 50
#define HDIM 128
#define NLAYER 4
#define ZDIM (2 * DIM + EDIM)  // 178
#define NTILES (N_EDGES / 32)  // 25000
#define MP 34                  // msgW row pitch (floats)

typedef __attribute__((ext_vector_type(8))) short short8v;
typedef __attribute__((ext_vector_type(16))) float f32x16;

__device__ __forceinline__ float softplus_f(float x) {
    return fmaxf(x, 0.0f) + log1pf(__expf(-fabsf(x)));
}

__device__ __forceinline__ short cvt_bf16(float f) {
    __hip_bfloat16 h = __float2bfloat16(f);
    return *reinterpret_cast<short*>(&h);
}

// h[n][d] = emb[x[n]][d]
__global__ void k_embed(const int* __restrict__ x, const float* __restrict__ emb,
                        float* __restrict__ h) {
    int i = blockIdx.x * 256 + threadIdx.x;
    int n = i >> 6, d = i & 63;
    h[i] = emb[x[n] * DIM + d];
}

// wcat[l][k][2*d+g] = (k<50) ? W_g[l][128+k][d] : 0
__global__ void k_wcat(const float* __restrict__ Wf, const float* __restrict__ Ws,
                       short* __restrict__ wcat) {
    int i = blockIdx.x * 256 + threadIdx.x;  // 4*64*128 = 32768
    int l = i >> 13;
    int rem = i & 8191;
    int k = rem >> 7;
    int colv = rem & 127;
    int d = colv >> 1, g = colv & 1;
    float v = 0.0f;
    if (k < 50) {
        const float* W = g ? Ws : Wf;
        v = W[((size_t)l * ZDIM + 128 + k) * 64 + d];
    }
    wcat[i] = cvt_bf16(v);
}

// ---------------- dst-sort (counting sort) ----------------
__global__ void k_hist(const int* __restrict__ eidx, int* __restrict__ hist) {
    int e = blockIdx.x * 256 + threadIdx.x;  // E exact
    atomicAdd(&hist[eidx[N_EDGES + e]], 1);
}

__global__ __launch_bounds__(256) void k_scan1(const int* __restrict__ hist,
                                               int* __restrict__ scanbuf,
                                               int* __restrict__ blocksums) {
    int tid = threadIdx.x;
    int i = blockIdx.x * 256 + tid;
    int v = (i < N_NODES) ? hist[i] : 0;
    int lane = tid & 63;
#pragma unroll
    for (int off = 1; off < 64; off <<= 1) {
        int u = __shfl_up(v, off);
        if (lane >= off) v += u;
    }
    __shared__ int wsum[4];
    if (lane == 63) wsum[tid >> 6] = v;
    __syncthreads();
    int w = tid >> 6;
    int add = 0;
#pragma unroll
    for (int k = 0; k < 3; ++k)
        if (k < w) add += wsum[k];
    v += add;
    if (i < N_NODES) scanbuf[i] = v;
    if (tid == 255) blocksums[blockIdx.x] = v;
}

__global__ __launch_bounds__(256) void k_scan2(int* __restrict__ blocksums, int nb) {
    int tid = threadIdx.x;
    int v = (tid < nb) ? blocksums[tid] : 0;
    int lane = tid & 63;
#pragma unroll
    for (int off = 1; off < 64; off <<= 1) {
        int u = __shfl_up(v, off);
        if (lane >= off) v += u;
    }
    __shared__ int wsum[4];
    if (lane == 63) wsum[tid >> 6] = v;
    __syncthreads();
    int w = tid >> 6;
    int add = 0;
#pragma unroll
    for (int k = 0; k < 3; ++k)
        if (k < w) add += wsum[k];
    v += add;
    if (tid < nb) blocksums[tid] = v;
}

__global__ void k_scan3(const int* __restrict__ scanbuf, const int* __restrict__ hist,
                        const int* __restrict__ blocksums, int* __restrict__ cursor) {
    int i = blockIdx.x * 256 + threadIdx.x;
    if (i >= N_NODES) return;
    int b = blockIdx.x;
    int off = b ? blocksums[b - 1] : 0;
    cursor[i] = scanbuf[i] - hist[i] + off;
}

__global__ void k_scatter(const int* __restrict__ eidx, int* __restrict__ cursor,
                          int* __restrict__ perm, int* __restrict__ permSrc,
                          int* __restrict__ permDst) {
    int e = blockIdx.x * 256 + threadIdx.x;
    int d = eidx[N_EDGES + e];
    int pos = atomicAdd(&cursor[d], 1);
    perm[pos] = e;
    permDst[pos] = d;
    permSrc[pos] = eidx[e];
}

// Fast sorted pack: thread = (tile, lane); handles all 4 kk fragments.
__global__ __launch_bounds__(256) void k_eprep2(const float* __restrict__ eattr,
                                                const int* __restrict__ perm,
                                                short* __restrict__ eattrP) {
    int i = blockIdx.x * 256 + threadIdx.x;  // over NTILES*64 = 1.6M
    int lane = i & 63;
    int tile = i >> 6;
    int pos = tile * 32 + (lane & 31);
    int h2 = lane >> 5;
    int edge = perm[pos];
    const float* erow = eattr + (size_t)edge * EDIM;  // byte base 200*edge: 8B-aligned
    int k0 = 8 * h2;
    float2 v[12];
#pragma unroll
    for (int kk = 0; kk < 3; ++kk) {
#pragma unroll
        for (int p = 0; p < 4; ++p) {
            v[kk * 4 + p] = *(const float2*)(erow + k0 + 16 * kk + 2 * p);
        }
    }
    float2 t48 = make_float2(0.0f, 0.0f);
    if (h2 == 0) t48 = *(const float2*)(erow + 48);

    size_t fb = ((size_t)tile * 4) * 64 + lane;  // fragment slot for kk=0
#pragma unroll
    for (int kk = 0; kk < 3; ++kk) {
        short8v o;
#pragma unroll
        for (int p = 0; p < 4; ++p) {
            o[2 * p] = cvt_bf16(v[kk * 4 + p].x);
            o[2 * p + 1] = cvt_bf16(v[kk * 4 + p].y);
        }
        *(short8v*)&eattrP[(fb + (size_t)kk * 64) * 8] = o;
    }
    short8v o;
#pragma unroll
    for (int e = 0; e < 8; ++e) o[e] = 0;
    o[0] = cvt_bf16(t48.x);
    o[1] = cvt_bf16(t48.y);
    *(short8v*)&eattrP[(fb + 3 * 64) * 8] = o;
}

// fallback pack (natural order), only used if ws too small for sort
__global__ void k_eprep(const float* __restrict__ eattr, short* __restrict__ eattrP) {
    int i = blockIdx.x * 256 + threadIdx.x;
    int lane = i & 63;
    int kk = (i >> 6) & 3;
    int tile = i >> 8;
    int edge = tile * 32 + (lane & 31);
    int k0 = kk * 16 + 8 * (lane >> 5);
    const float* erow = eattr + (size_t)edge * EDIM;
    short8v v;
#pragma unroll
    for (int j = 0; j < 8; ++j) {
        int k = k0 + j;
        float f = (k < EDIM) ? erow[k] : 0.0f;
        v[j] = cvt_bf16(f);
    }
    *(short8v*)&eattrP[(size_t)i * 8] = v;
}

// Per-layer node-side matmuls (bias folded into dstpack).
__global__ __launch_bounds__(256) void k_nodemm(
    const float* __restrict__ h,
    const float* __restrict__ Wf, const float* __restrict__ bf,
    const float* __restrict__ Ws, const float* __restrict__ bs,
    float* __restrict__ dstpack, float* __restrict__ srcpack) {
    __shared__ float hs[64 * 68];
    int tid = threadIdx.x;
    int w = tid >> 6, lane = tid & 63;
    int n0 = blockIdx.x * 64;
    for (int idx = tid; idx < 64 * 64; idx += 256) {
        int i = idx >> 6, k = idx & 63;
        int n = n0 + i;
        hs[i * 68 + k] = (n < N_NODES) ? h[n * DIM + k] : 0.0f;
    }
    __syncthreads();
    int colv = (w & 1) * 64 + lane;  // 0..127
    int d = colv >> 1, g = colv & 1;
    const float* Wsel = g ? Ws : Wf;
    int row0 = (w < 2) ? 0 : 64;
    float wcol[64];
#pragma unroll
    for (int k = 0; k < 64; ++k) wcol[k] = Wsel[(row0 + k) * 64 + d];
    float bias = (w < 2) ? (g ? bs[d] : bf[d]) : 0.0f;
    float* outp = (w < 2) ? dstpack : srcpack;
    int nmax = min(64, N_NODES - n0);
    for (int i = 0; i < nmax; ++i) {
        float acc = bias;
#pragma unroll
        for (int k = 0; k < 64; k += 4) {
            float4 hv = *(const float4*)&hs[i * 68 + k];
            acc += hv.x * wcol[k] + hv.y * wcol[k + 1] + hv.z * wcol[k + 2] + hv.w * wcol[k + 3];
        }
        outp[(size_t)(n0 + i) * 128 + colv] = acc;
    }
}

// ---------------- sorted edge kernel with LDS segmented reduction ----------------
__global__ __launch_bounds__(256) void k_edge_s(
    const int* __restrict__ permSrc,    // [E] sorted by dst
    const int* __restrict__ permDst,    // [E] sorted (non-decreasing)
    const short* __restrict__ eattrP,   // packed A-fragments (sorted order)
    const float* __restrict__ dstpack,  // [N][128]
    const float* __restrict__ srcpack,  // [N][128]
    const short* __restrict__ wcat_l,   // [64][128] bf16
    float* __restrict__ agg) {          // [N][64]
    __shared__ float msgW[4][32][MP];
    __shared__ int dshI[4][32];
    int tid = threadIdx.x;
    int w = tid >> 6;
    int lane = tid & 63;
    int c = lane & 31;
    int h2 = lane >> 5;
    int col = w * 32 + c;

    short8v bfr[4];
#pragma unroll
    for (int kk = 0; kk < 4; ++kk) {
#pragma unroll
        for (int e = 0; e < 8; ++e) {
            bfr[kk][e] = wcat_l[(kk * 16 + 8 * h2 + e) * 128 + col];
        }
    }

    for (int tile = blockIdx.x; tile < NTILES; tile += gridDim.x) {
        int e0 = tile * 32;

        if (lane < 32) dshI[w][lane] = permDst[e0 + lane];

        short8v afr[4];
#pragma unroll
        for (int kk = 0; kk < 4; ++kk) {
            afr[kk] = *(const short8v*)&eattrP[(((size_t)tile * 4 + kk) * 64 + lane) * 8];
        }

        f32x16 acc;
#pragma unroll
        for (int i = 0; i < 16; ++i) acc[i] = 0.0f;
#pragma unroll
        for (int kk = 0; kk < 4; ++kk) {
            acc = __builtin_amdgcn_mfma_f32_32x32x16_bf16(afr[kk], bfr[kk], acc, 0, 0, 0);
        }

#pragma unroll
        for (int grp = 0; grp < 2; ++grp) {
            int tI[8], sI[8];
            float dv[8], sv[8];
#pragma unroll
            for (int r = 0; r < 8; ++r) {
                int rr = grp * 8 + r;
                int row = (rr & 3) + 8 * (rr >> 2) + 4 * h2;
                sI[r] = permSrc[e0 + row];
                tI[r] = permDst[e0 + row];
            }
#pragma unroll
            for (int r = 0; r < 8; ++r) {
                dv[r] = dstpack[(size_t)tI[r] * 128 + col];
                sv[r] = srcpack[(size_t)sI[r] * 128 + col];
            }
#pragma unroll
            for (int r = 0; r < 8; ++r) {
                int rr = grp * 8 + r;
                int row = (rr & 3) + 8 * (rr >> 2) + 4 * h2;
                float pre = acc[rr] + dv[r] + sv[r];
                float e = __expf(-fabsf(pre));
                float q = 1.0f + e;
                float val;
                if (c & 1) {
                    val = fmaxf(pre, 0.0f) + __logf(q);  // softplus
                } else {
                    float inv = __builtin_amdgcn_rcpf(q);
                    val = (pre >= 0.0f) ? inv : e * inv;  // sigmoid
                }
                msgW[w][row][c] = val;
            }
        }

        __builtin_amdgcn_wave_barrier();

        {
            int dd = lane & 15;
            int base = (lane >> 4) * 8;
            float accum = 0.0f;
            int cur = dshI[w][base];
#pragma unroll
            for (int j = 0; j < 8; ++j) {
                int row = base + j;
                float2 ms = *(const float2*)&msgW[w][row][2 * dd];
                int dn = dshI[w][row];
                if (dn != cur) {
                    unsafeAtomicAdd(&agg[(size_t)cur * 64 + (w * 16 + dd)], accum);
                    accum = 0.0f;
                    cur = dn;
                }
                accum += ms.x * ms.y;
            }
            unsafeAtomicAdd(&agg[(size_t)cur * 64 + (w * 16 + dd)], accum);
        }
        __builtin_amdgcn_wave_barrier();
    }
}

// fallback edge kernel (unsorted, per-element atomics)
template <bool PACKED>
__global__ __launch_bounds__(256) void k_edge(
    const int* __restrict__ eidx, const float* __restrict__ eattr,
    const short* __restrict__ eattrP, const float* __restrict__ dstpack,
    const float* __restrict__ srcpack, const short* __restrict__ wcat_l,
    float* __restrict__ agg) {
    int tid = threadIdx.x;
    int w = tid >> 6;
    int lane = tid & 63;
    int c = lane & 31;
    int h2 = lane >> 5;
    int col = w * 32 + c;
    short8v bfr[4];
#pragma unroll
    for (int kk = 0; kk < 4; ++kk) {
#pragma unroll
        for (int e = 0; e < 8; ++e) bfr[kk][e] = wcat_l[(kk * 16 + 8 * h2 + e) * 128 + col];
    }
    for (int tile = blockIdx.x; tile < NTILES; tile += gridDim.x) {
        int e0 = tile * 32;
        short8v afr[4];
        if (PACKED) {
#pragma unroll
            for (int kk = 0; kk < 4; ++kk)
                afr[kk] = *(const short8v*)&eattrP[(((size_t)tile * 4 + kk) * 64 + lane) * 8];
        } else {
            const float* erow = eattr + (size_t)(e0 + c) * EDIM;
#pragma unroll
            for (int kk = 0; kk < 3; ++kk) {
                int k0 = kk * 16 + 8 * h2;
#pragma unroll
                for (int p = 0; p < 4; ++p) {
                    float2 v = *(const float2*)(erow + k0 + 2 * p);
                    afr[kk][2 * p] = cvt_bf16(v.x);
                    afr[kk][2 * p + 1] = cvt_bf16(v.y);
                }
            }
            short8v a;
#pragma unroll
            for (int e = 0; e < 8; ++e) a[e] = 0;
            if (h2 == 0) {
                float2 v = *(const float2*)(erow + 48);
                a[0] = cvt_bf16(v.x);
                a[1] = cvt_bf16(v.y);
            }
            afr[3] = a;
        }
        f32x16 acc;
#pragma unroll
        for (int i = 0; i < 16; ++i) acc[i] = 0.0f;
#pragma unroll
        for (int kk = 0; kk < 4; ++kk)
            acc = __builtin_amdgcn_mfma_f32_32x32x16_bf16(afr[kk], bfr[kk], acc, 0, 0, 0);
#pragma unroll
        for (int grp = 0; grp < 2; ++grp) {
            int tI[8], sI[8];
            float dv[8], sv[8];
#pragma unroll
            for (int r = 0; r < 8; ++r) {
                int rr = grp * 8 + r;
                int row = (rr & 3) + 8 * (rr >> 2) + 4 * h2;
                sI[r] = eidx[e0 + row];
                tI[r] = eidx[N_EDGES + e0 + row];
            }
#pragma unroll
            for (int r = 0; r < 8; ++r) {
                dv[r] = dstpack[(size_t)tI[r] * 128 + col];
                sv[r] = srcpack[(size_t)sI[r] * 128 + col];
            }
#pragma unroll
            for (int r = 0; r < 8; ++r) {
                float pre = acc[grp * 8 + r] + dv[r] + sv[r];
                float e = __expf(-fabsf(pre));
                float q = 1.0f + e;
                float inv = __builtin_amdgcn_rcpf(q);
                float sig = (pre >= 0.0f) ? inv : e * inv;
                float sp = fmaxf(pre, 0.0f) + __logf(q);
                float mine = (c & 1) ? sp : sig;
                float partner = __shfl_xor(mine, 1);
                if (!(c & 1)) unsafeAtomicAdd(&agg[(size_t)tI[r] * 64 + (col >> 1)], sig * partner);
            }
        }
    }
}

// h = softplus(h + agg); re-zero agg for the next layer
__global__ void k_update(float* __restrict__ h, float* __restrict__ agg) {
    int i = blockIdx.x * 256 + threadIdx.x;
    h[i] = softplus_f(h[i] + agg[i]);
    agg[i] = 0.0f;
}

// Sorted-batch pool: per-thread run-length accumulation, one atomic per
// graph transition instead of one per node. batch is non-decreasing.
__global__ __launch_bounds__(256) void k_pool_s(
    const float* __restrict__ h, const int* __restrict__ batch,
    float* __restrict__ pooled, float* __restrict__ counts) {
    int tid = threadIdx.x;
    int d = tid & 63;
    int strm = tid >> 6;
    int base = blockIdx.x * 256 + strm * 64;
    if (base >= N_NODES) return;
    int end = min(base + 64, N_NODES);
    float accum = 0.0f;
    int cnt = 0;
    int cur = batch[base];
#pragma unroll 4
    for (int n = base; n < end; ++n) {
        int g = batch[n];
        if (g != cur) {
            unsafeAtomicAdd(&pooled[cur * DIM + d], accum);
            if (d == 0) unsafeAtomicAdd(&counts[cur], (float)cnt);
            accum = 0.0f;
            cnt = 0;
            cur = g;
        }
        accum += h[(size_t)n * DIM + d];
        cnt++;
    }
    unsafeAtomicAdd(&pooled[cur * DIM + d], accum);
    if (d == 0) unsafeAtomicAdd(&counts[cur], (float)cnt);
}

__global__ __launch_bounds__(64) void k_mlp(
    const float* __restrict__ pooled, const float* __restrict__ counts,
    const float* __restrict__ W1, const float* __restrict__ b1,
    const float* __restrict__ W2, const float* __restrict__ b2,
    const float* __restrict__ Wo, const float* __restrict__ bo,
    float* __restrict__ out) {
    __shared__ float ps[64];
    __shared__ float h1[128];
    int g = blockIdx.x, lane = threadIdx.x;
    float cnt = fmaxf(counts[g], 1.0f);
    ps[lane] = pooled[g * DIM + lane] / cnt;
    __syncthreads();
#pragma unroll
    for (int rep = 0; rep < 2; ++rep) {
        int j = lane + rep * 64;
        float acc = b1[j];
        for (int k = 0; k < 64; ++k) acc += ps[k] * W1[k * HDIM + j];
        h1[j] = fmaxf(acc, 0.0f);
    }
    __syncthreads();
    float acc = b2[lane];
    for (int k = 0; k < 128; ++k) acc += h1[k] * W2[k * 64 + lane];
    float v = fmaxf(acc, 0.0f) * Wo[lane];
#pragma unroll
    for (int off = 32; off; off >>= 1) v += __shfl_down(v, off);
    if (lane == 0) out[g] = v + bo[0];
}

extern "C" void kernel_launch(void* const* d_in, const int* in_sizes, int n_in,
                              void* d_out, int out_size, void* d_ws, size_t ws_size,
                              hipStream_t stream) {
    const int* x = (const int*)d_in[0];
    const int* eidx = (const int*)d_in[1];
    const float* eattr = (const float*)d_in[2];
    const int* batch = (const int*)d_in[3];
    const float* emb = (const float*)d_in[4];
    const float* Wf = (const float*)d_in[5];
    const float* bf = (const float*)d_in[6];
    const float* Ws = (const float*)d_in[7];
    const float* bs = (const float*)d_in[8];
    const float* W1 = (const float*)d_in[9];
    const float* b1 = (const float*)d_in[10];
    const float* W2 = (const float*)d_in[11];
    const float* b2 = (const float*)d_in[12];
    const float* Wo = (const float*)d_in[13];
    const float* bo = (const float*)d_in[14];
    float* out = (float*)d_out;

    char* p = (char*)d_ws;
    float* h = (float*)p;       p += (size_t)N_NODES * DIM * 4;
    float* dstpack = (float*)p; p += (size_t)N_NODES * 2 * DIM * 4;
    float* srcpack = (float*)p; p += (size_t)N_NODES * 2 * DIM * 4;
    float* agg = (float*)p;     p += (size_t)N_NODES * DIM * 4;
    float* pooled = (float*)p;  p += (size_t)N_GRAPHS * DIM * 4;
    float* counts = (float*)p;  p += (size_t)N_GRAPHS * 4;
    short* wcat = (short*)p;    p += (size_t)NLAYER * 64 * 128 * 2;
    short* eattrP = (short*)p;  p += (size_t)NTILES * 4 * 64 * 8 * 2;  // 102.4 MB
    size_t used_packed = (size_t)(p - (char*)d_ws);
    int* hist = (int*)p;        p += (size_t)N_NODES * 4;
    int* scanbuf = (int*)p;     p += (size_t)N_NODES * 4;
    int* blocksums = (int*)p;   p += 256 * 4;
    int* cursor = (int*)p;      p += (size_t)N_NODES * 4;
    int* perm = (int*)p;        p += (size_t)N_EDGES * 4;
    int* permSrc = (int*)p;     p += (size_t)N_EDGES * 4;
    int* permDst = (int*)p;     p += (size_t)N_EDGES * 4;
    size_t used_sorted = (size_t)(p - (char*)d_ws);

    bool packed = used_packed <= ws_size;
    bool sorted = used_sorted <= ws_size;

    const int SCAN_BLOCKS = (N_NODES + 255) / 256;  // 196

    k_embed<<<N_NODES * DIM / 256, 256, 0, stream>>>(x, emb, h);
    k_wcat<<<NLAYER * 64 * 128 / 256, 256, 0, stream>>>(Wf, Ws, wcat);
    if (sorted) {
        hipMemsetAsync(hist, 0, (size_t)N_NODES * 4, stream);
        k_hist<<<N_EDGES / 256, 256, 0, stream>>>(eidx, hist);
        k_scan1<<<SCAN_BLOCKS, 256, 0, stream>>>(hist, scanbuf, blocksums);
        k_scan2<<<1, 256, 0, stream>>>(blocksums, SCAN_BLOCKS);
        k_scan3<<<SCAN_BLOCKS, 256, 0, stream>>>(scanbuf, hist, blocksums, cursor);
        k_scatter<<<N_EDGES / 256, 256, 0, stream>>>(eidx, cursor, perm, permSrc, permDst);
        k_eprep2<<<NTILES * 64 / 256, 256, 0, stream>>>(eattr, perm, eattrP);
    } else if (packed) {
        k_eprep<<<NTILES, 256, 0, stream>>>(eattr, eattrP);
    }
    hipMemsetAsync(agg, 0, (size_t)N_NODES * DIM * 4, stream);
    for (int l = 0; l < NLAYER; ++l) {
        const float* Wfl = Wf + (size_t)l * ZDIM * DIM;
        const float* Wsl = Ws + (size_t)l * ZDIM * DIM;
        k_nodemm<<<(N_NODES + 63) / 64, 256, 0, stream>>>(
            h, Wfl, bf + l * DIM, Wsl, bs + l * DIM, dstpack, srcpack);
        if (sorted) {
            k_edge_s<<<2048, 256, 0, stream>>>(permSrc, permDst, eattrP, dstpack, srcpack,
                                               wcat + (size_t)l * 64 * 128, agg);
        } else if (packed) {
            k_edge<true><<<2048, 256, 0, stream>>>(eidx, eattr, eattrP, dstpack, srcpack,
                                                   wcat + (size_t)l * 64 * 128, agg);
        } else {
            k_edge<false><<<2048, 256, 0, stream>>>(eidx, eattr, eattrP, dstpack, srcpack,
                                                    wcat + (size_t)l * 64 * 128, agg);
        }
        k_update<<<N_NODES * DIM / 256, 256, 0, stream>>>(h, agg);
    }
    hipMemsetAsync(pooled, 0, ((size_t)N_GRAPHS * DIM + N_GRAPHS) * 4, stream);
    k_pool_s<<<(N_NODES + 255) / 256, 256, 0, stream>>>(h, batch, pooled, counts);
    k_mlp<<<N_GRAPHS, 64, 0, stream>>>(pooled, counts, W1, b1, W2, b2, Wo, bo, out);
}

// Round 7
// 919.304 us; speedup vs baseline: 2.5176x; 1.1663x over previous
//
#include <hip/hip_runtime.h>
#include <hip/hip_bf16.h>
#include <math.h>

#define N_NODES 50000
#define N_EDGES 800000
#define N_GRAPHS 256
#define DIM 64
#define EDIM 50
#define HDIM 128
#define NLAYER 4
#define ZDIM (2 * DIM + EDIM)  // 178
#define NTILES (N_EDGES / 32)  // 25000

typedef __attribute__((ext_vector_type(8))) short short8v;
typedef __attribute__((ext_vector_type(16))) float f32x16;

__device__ __forceinline__ float softplus_f(float x) {
    return fmaxf(x, 0.0f) + log1pf(__expf(-fabsf(x)));
}

__device__ __forceinline__ short cvt_bf16(float f) {
    __hip_bfloat16 h = __float2bfloat16(f);
    return *reinterpret_cast<short*>(&h);
}

// Weight tiles, NEW column layout: colv = g*64 + d  (g: 0=sigmoid/Wf, 1=softplus/Ws)
// wcat[l][k][colv] = (k<50) ? W_g[l][128+k][d] : 0   (k padded to 64)
__global__ void k_wcat(const float* __restrict__ Wf, const float* __restrict__ Ws,
                       short* __restrict__ wcat) {
    int i = blockIdx.x * 256 + threadIdx.x;  // 4*64*128 = 32768
    int l = i >> 13;
    int rem = i & 8191;
    int k = rem >> 7;
    int colv = rem & 127;
    int g = colv >> 6, d = colv & 63;
    float v = 0.0f;
    if (k < 50) {
        const float* W = g ? Ws : Wf;
        v = W[((size_t)l * ZDIM + 128 + k) * 64 + d];
    }
    wcat[i] = cvt_bf16(v);
}

// ---------------- dst-sort (counting sort) ----------------
__global__ void k_hist(const int* __restrict__ eidx, int* __restrict__ hist) {
    int e = blockIdx.x * 256 + threadIdx.x;  // E exact
    atomicAdd(&hist[eidx[N_EDGES + e]], 1);
}

__global__ __launch_bounds__(256) void k_scan1(const int* __restrict__ hist,
                                               int* __restrict__ scanbuf,
                                               int* __restrict__ blocksums) {
    int tid = threadIdx.x;
    int i = blockIdx.x * 256 + tid;
    int v = (i < N_NODES) ? hist[i] : 0;
    int lane = tid & 63;
#pragma unroll
    for (int off = 1; off < 64; off <<= 1) {
        int u = __shfl_up(v, off);
        if (lane >= off) v += u;
    }
    __shared__ int wsum[4];
    if (lane == 63) wsum[tid >> 6] = v;
    __syncthreads();
    int w = tid >> 6;
    int add = 0;
#pragma unroll
    for (int k = 0; k < 3; ++k)
        if (k < w) add += wsum[k];
    v += add;
    if (i < N_NODES) scanbuf[i] = v;
    if (tid == 255) blocksums[blockIdx.x] = v;
}

__global__ __launch_bounds__(256) void k_scan2(int* __restrict__ blocksums, int nb) {
    int tid = threadIdx.x;
    int v = (tid < nb) ? blocksums[tid] : 0;
    int lane = tid & 63;
#pragma unroll
    for (int off = 1; off < 64; off <<= 1) {
        int u = __shfl_up(v, off);
        if (lane >= off) v += u;
    }
    __shared__ int wsum[4];
    if (lane == 63) wsum[tid >> 6] = v;
    __syncthreads();
    int w = tid >> 6;
    int add = 0;
#pragma unroll
    for (int k = 0; k < 3; ++k)
        if (k < w) add += wsum[k];
    v += add;
    if (tid < nb) blocksums[tid] = v;
}

__global__ void k_scan3(const int* __restrict__ scanbuf, const int* __restrict__ hist,
                        const int* __restrict__ blocksums, int* __restrict__ cursor) {
    int i = blockIdx.x * 256 + threadIdx.x;
    if (i >= N_NODES) return;
    int b = blockIdx.x;
    int off = b ? blocksums[b - 1] : 0;
    cursor[i] = scanbuf[i] - hist[i] + off;
}

__global__ void k_scatter(const int* __restrict__ eidx, int* __restrict__ cursor,
                          int* __restrict__ perm, int* __restrict__ permSrc,
                          int* __restrict__ permDst) {
    int e = blockIdx.x * 256 + threadIdx.x;
    int d = eidx[N_EDGES + e];
    int pos = atomicAdd(&cursor[d], 1);
    perm[pos] = e;
    permDst[pos] = d;
    permSrc[pos] = eidx[e];
}

// Sorted pack: thread = (tile, lane); handles all 4 kk fragments.
__global__ __launch_bounds__(256) void k_eprep2(const float* __restrict__ eattr,
                                                const int* __restrict__ perm,
                                                short* __restrict__ eattrP) {
    int i = blockIdx.x * 256 + threadIdx.x;  // over NTILES*64 = 1.6M
    int lane = i & 63;
    int tile = i >> 6;
    int pos = tile * 32 + (lane & 31);
    int h2 = lane >> 5;
    int edge = perm[pos];
    const float* erow = eattr + (size_t)edge * EDIM;  // 8B-aligned (200*edge)
    int k0 = 8 * h2;
    float2 v[12];
#pragma unroll
    for (int kk = 0; kk < 3; ++kk) {
#pragma unroll
        for (int p = 0; p < 4; ++p) {
            v[kk * 4 + p] = *(const float2*)(erow + k0 + 16 * kk + 2 * p);
        }
    }
    float2 t48 = make_float2(0.0f, 0.0f);
    if (h2 == 0) t48 = *(const float2*)(erow + 48);

    size_t fb = ((size_t)tile * 4) * 64 + lane;
#pragma unroll
    for (int kk = 0; kk < 3; ++kk) {
        short8v o;
#pragma unroll
        for (int p = 0; p < 4; ++p) {
            o[2 * p] = cvt_bf16(v[kk * 4 + p].x);
            o[2 * p + 1] = cvt_bf16(v[kk * 4 + p].y);
        }
        *(short8v*)&eattrP[(fb + (size_t)kk * 64) * 8] = o;
    }
    short8v o;
#pragma unroll
    for (int e = 0; e < 8; ++e) o[e] = 0;
    o[0] = cvt_bf16(t48.x);
    o[1] = cvt_bf16(t48.y);
    *(short8v*)&eattrP[(fb + 3 * 64) * 8] = o;
}

// Node-side matmuls, output layout [n][colv], colv = g*64+d.
// wave 0: dst g=0 (Wf rows 0..63, +bf) | wave 1: dst g=1 (Ws, +bs)
// wave 2: src g=0 (Wf rows 64..127)    | wave 3: src g=1 (Ws rows 64..127)
// MODE 0: read h.  MODE 1: v=softplus(h+agg), write h, zero agg (fused update).
// MODE 2: v=emb[x[n]], write h (fused embed).
template <int MODE>
__global__ __launch_bounds__(256) void k_nodemm(
    const float* __restrict__ hin, float* __restrict__ hout, float* __restrict__ agg,
    const int* __restrict__ x, const float* __restrict__ emb,
    const float* __restrict__ Wf, const float* __restrict__ bf,
    const float* __restrict__ Ws, const float* __restrict__ bs,
    float* __restrict__ dstpack, float* __restrict__ srcpack) {
    __shared__ float hs[64 * 68];
    int tid = threadIdx.x;
    int w = tid >> 6, lane = tid & 63;
    int n0 = blockIdx.x * 64;
    for (int idx = tid; idx < 64 * 64; idx += 256) {
        int i = idx >> 6, k = idx & 63;
        int n = n0 + i;
        float v = 0.0f;
        if (n < N_NODES) {
            if (MODE == 0) {
                v = hin[(size_t)n * DIM + k];
            } else if (MODE == 1) {
                v = softplus_f(hin[(size_t)n * DIM + k] + agg[(size_t)n * DIM + k]);
                agg[(size_t)n * DIM + k] = 0.0f;
                hout[(size_t)n * DIM + k] = v;
            } else {
                v = emb[x[n] * DIM + k];
                hout[(size_t)n * DIM + k] = v;
            }
        }
        hs[i * 68 + k] = v;
    }
    __syncthreads();
    const float* Wsel = (w & 1) ? Ws : Wf;
    int row0 = (w < 2) ? 0 : 64;
    float wcol[64];
#pragma unroll
    for (int k = 0; k < 64; ++k) wcol[k] = Wsel[(row0 + k) * 64 + lane];
    float bias = (w == 0) ? bf[lane] : (w == 1) ? bs[lane] : 0.0f;
    float* outp = (w < 2) ? dstpack : srcpack;
    int colv = (w & 1) * 64 + lane;
    int nmax = min(64, N_NODES - n0);
    for (int i = 0; i < nmax; ++i) {
        float acc = bias;
#pragma unroll
        for (int k = 0; k < 64; k += 4) {
            float4 hv = *(const float4*)&hs[i * 68 + k];
            acc += hv.x * wcol[k] + hv.y * wcol[k + 1] + hv.z * wcol[k + 2] + hv.w * wcol[k + 3];
        }
        outp[(size_t)(n0 + i) * 128 + colv] = acc;
    }
}

// ---------------- sorted edge kernel, wave-uniform gates ----------------
// waves 0,1 -> sigmoid (g=0, cols 0..63); waves 2,3 -> softplus (g=1, cols 64..127)
__global__ __launch_bounds__(256) void k_edge_s(
    const int* __restrict__ permSrc, const int* __restrict__ permDst,
    const short* __restrict__ eattrP, const float* __restrict__ dstpack,
    const float* __restrict__ srcpack, const short* __restrict__ wcat_l,
    float* __restrict__ agg) {
    __shared__ float msgV[2][32][64];
    __shared__ int dsh[32], ssh[32];
    int tid = threadIdx.x;
    int w = tid >> 6;
    int lane = tid & 63;
    int c = lane & 31;
    int h2 = lane >> 5;
    int col = w * 32 + c;
    int dcol = (w & 1) * 32 + c;

    short8v bfr[4];
#pragma unroll
    for (int kk = 0; kk < 4; ++kk) {
#pragma unroll
        for (int e = 0; e < 8; ++e) {
            bfr[kk][e] = wcat_l[(kk * 16 + 8 * h2 + e) * 128 + col];
        }
    }

    for (int tile = blockIdx.x; tile < NTILES; tile += gridDim.x) {
        int e0 = tile * 32;

        // all 4 waves redundantly write identical index arrays (benign)
        if (lane < 32) {
            dsh[lane] = permDst[e0 + lane];
            ssh[lane] = permSrc[e0 + lane];
        }

        short8v afr[4];
#pragma unroll
        for (int kk = 0; kk < 4; ++kk) {
            afr[kk] = *(const short8v*)&eattrP[(((size_t)tile * 4 + kk) * 64 + lane) * 8];
        }

        f32x16 acc;
#pragma unroll
        for (int i = 0; i < 16; ++i) acc[i] = 0.0f;
#pragma unroll
        for (int kk = 0; kk < 4; ++kk) {
            acc = __builtin_amdgcn_mfma_f32_32x32x16_bf16(afr[kk], bfr[kk], acc, 0, 0, 0);
        }

        __builtin_amdgcn_wave_barrier();  // keep dsh/ssh writes before reads below

        // C/D layout (32x32): col = lane&31, row = (r&3)+8*(r>>2)+4*h2
#pragma unroll
        for (int grp = 0; grp < 2; ++grp) {
            int tI[8], sI[8];
            float dv[8], sv[8];
#pragma unroll
            for (int r = 0; r < 8; ++r) {
                int rr = grp * 8 + r;
                int row = (rr & 3) + 8 * (rr >> 2) + 4 * h2;
                tI[r] = dsh[row];
                sI[r] = ssh[row];
            }
#pragma unroll
            for (int r = 0; r < 8; ++r) {
                dv[r] = dstpack[(unsigned)((tI[r] << 7) + col)];
                sv[r] = srcpack[(unsigned)((sI[r] << 7) + col)];
            }
            float pre[8];
#pragma unroll
            for (int r = 0; r < 8; ++r) pre[r] = acc[grp * 8 + r] + dv[r] + sv[r];
            if (w < 2) {  // wave-uniform: sigmoid only
#pragma unroll
                for (int r = 0; r < 8; ++r) {
                    int rr = grp * 8 + r;
                    int row = (rr & 3) + 8 * (rr >> 2) + 4 * h2;
                    float e = __expf(-fabsf(pre[r]));
                    float inv = __builtin_amdgcn_rcpf(1.0f + e);
                    msgV[0][row][dcol] = (pre[r] >= 0.0f) ? inv : e * inv;
                }
            } else {  // wave-uniform: softplus only
#pragma unroll
                for (int r = 0; r < 8; ++r) {
                    int rr = grp * 8 + r;
                    int row = (rr & 3) + 8 * (rr >> 2) + 4 * h2;
                    float e = __expf(-fabsf(pre[r]));
                    msgV[1][row][dcol] = fmaxf(pre[r], 0.0f) + __logf(1.0f + e);
                }
            }
        }

        __syncthreads();

        // paired segmented scan: thread -> (d = tid&63, rows (tid>>6)*8 .. +8)
        {
            int d = tid & 63;
            int base = (tid >> 6) * 8;
            float accum = 0.0f;
            int cur = dsh[base];
#pragma unroll
            for (int j = 0; j < 8; ++j) {
                int row = base + j;
                float m = msgV[0][row][d] * msgV[1][row][d];
                int dn = dsh[row];
                if (dn != cur) {
                    unsafeAtomicAdd(&agg[(unsigned)((cur << 6) + d)], accum);
                    accum = 0.0f;
                    cur = dn;
                }
                accum += m;
            }
            unsafeAtomicAdd(&agg[(unsigned)((cur << 6) + d)], accum);
        }
        __syncthreads();
    }
}

// Unsorted fallback (only if ws too small for the sort buffers): same structure,
// indices from eidx, eattr converted in-kernel, per-element atomics.
__global__ __launch_bounds__(256) void k_edge_u(
    const int* __restrict__ eidx, const float* __restrict__ eattr,
    const float* __restrict__ dstpack, const float* __restrict__ srcpack,
    const short* __restrict__ wcat_l, float* __restrict__ agg) {
    __shared__ float msgV[2][32][64];
    __shared__ int dsh[32], ssh[32];
    int tid = threadIdx.x;
    int w = tid >> 6;
    int lane = tid & 63;
    int c = lane & 31;
    int h2 = lane >> 5;
    int col = w * 32 + c;
    int dcol = (w & 1) * 32 + c;

    short8v bfr[4];
#pragma unroll
    for (int kk = 0; kk < 4; ++kk) {
#pragma unroll
        for (int e = 0; e < 8; ++e) bfr[kk][e] = wcat_l[(kk * 16 + 8 * h2 + e) * 128 + col];
    }

    for (int tile = blockIdx.x; tile < NTILES; tile += gridDim.x) {
        int e0 = tile * 32;
        if (lane < 32) {
            dsh[lane] = eidx[N_EDGES + e0 + lane];
            ssh[lane] = eidx[e0 + lane];
        }
        short8v afr[4];
        const float* erow = eattr + (size_t)(e0 + c) * EDIM;
#pragma unroll
        for (int kk = 0; kk < 3; ++kk) {
            int k0 = kk * 16 + 8 * h2;
#pragma unroll
            for (int p = 0; p < 4; ++p) {
                float2 v = *(const float2*)(erow + k0 + 2 * p);
                afr[kk][2 * p] = cvt_bf16(v.x);
                afr[kk][2 * p + 1] = cvt_bf16(v.y);
            }
        }
        {
            short8v a;
#pragma unroll
            for (int e = 0; e < 8; ++e) a[e] = 0;
            if (h2 == 0) {
                float2 v = *(const float2*)(erow + 48);
                a[0] = cvt_bf16(v.x);
                a[1] = cvt_bf16(v.y);
            }
            afr[3] = a;
        }
        f32x16 acc;
#pragma unroll
        for (int i = 0; i < 16; ++i) acc[i] = 0.0f;
#pragma unroll
        for (int kk = 0; kk < 4; ++kk)
            acc = __builtin_amdgcn_mfma_f32_32x32x16_bf16(afr[kk], bfr[kk], acc, 0, 0, 0);

        __builtin_amdgcn_wave_barrier();

#pragma unroll
        for (int grp = 0; grp < 2; ++grp) {
            int tI[8], sI[8];
            float dv[8], sv[8];
#pragma unroll
            for (int r = 0; r < 8; ++r) {
                int rr = grp * 8 + r;
                int row = (rr & 3) + 8 * (rr >> 2) + 4 * h2;
                tI[r] = dsh[row];
                sI[r] = ssh[row];
            }
#pragma unroll
            for (int r = 0; r < 8; ++r) {
                dv[r] = dstpack[(unsigned)((tI[r] << 7) + col)];
                sv[r] = srcpack[(unsigned)((sI[r] << 7) + col)];
            }
            float pre[8];
#pragma unroll
            for (int r = 0; r < 8; ++r) pre[r] = acc[grp * 8 + r] + dv[r] + sv[r];
            if (w < 2) {
#pragma unroll
                for (int r = 0; r < 8; ++r) {
                    int rr = grp * 8 + r;
                    int row = (rr & 3) + 8 * (rr >> 2) + 4 * h2;
                    float e = __expf(-fabsf(pre[r]));
                    float inv = __builtin_amdgcn_rcpf(1.0f + e);
                    msgV[0][row][dcol] = (pre[r] >= 0.0f) ? inv : e * inv;
                }
            } else {
#pragma unroll
                for (int r = 0; r < 8; ++r) {
                    int rr = grp * 8 + r;
                    int row = (rr & 3) + 8 * (rr >> 2) + 4 * h2;
                    float e = __expf(-fabsf(pre[r]));
                    msgV[1][row][dcol] = fmaxf(pre[r], 0.0f) + __logf(1.0f + e);
                }
            }
        }
        __syncthreads();
        {
            int d = tid & 63;
            int base = (tid >> 6) * 8;
#pragma unroll
            for (int j = 0; j < 8; ++j) {
                int row = base + j;
                float m = msgV[0][row][d] * msgV[1][row][d];
                unsafeAtomicAdd(&agg[(unsigned)((dsh[row] << 6) + d)], m);
            }
        }
        __syncthreads();
    }
}

// final update: h = softplus(h + agg); agg = 0
__global__ void k_update(float* __restrict__ h, float* __restrict__ agg) {
    int i = blockIdx.x * 256 + threadIdx.x;
    h[i] = softplus_f(h[i] + agg[i]);
    agg[i] = 0.0f;
}

// Sorted-batch pool: run-length accumulation, one atomic per graph transition.
__global__ __launch_bounds__(256) void k_pool_s(
    const float* __restrict__ h, const int* __restrict__ batch,
    float* __restrict__ pooled, float* __restrict__ counts) {
    int tid = threadIdx.x;
    int d = tid & 63;
    int strm = tid >> 6;
    int base = blockIdx.x * 256 + strm * 64;
    if (base >= N_NODES) return;
    int end = min(base + 64, N_NODES);
    float accum = 0.0f;
    int cnt = 0;
    int cur = batch[base];
#pragma unroll 4
    for (int n = base; n < end; ++n) {
        int g = batch[n];
        if (g != cur) {
            unsafeAtomicAdd(&pooled[cur * DIM + d], accum);
            if (d == 0) unsafeAtomicAdd(&counts[cur], (float)cnt);
            accum = 0.0f;
            cnt = 0;
            cur = g;
        }
        accum += h[(size_t)n * DIM + d];
        cnt++;
    }
    unsafeAtomicAdd(&pooled[cur * DIM + d], accum);
    if (d == 0) unsafeAtomicAdd(&counts[cur], (float)cnt);
}

__global__ __launch_bounds__(64) void k_mlp(
    const float* __restrict__ pooled, const float* __restrict__ counts,
    const float* __restrict__ W1, const float* __restrict__ b1,
    const float* __restrict__ W2, const float* __restrict__ b2,
    const float* __restrict__ Wo, const float* __restrict__ bo,
    float* __restrict__ out) {
    __shared__ float ps[64];
    __shared__ float h1[128];
    int g = blockIdx.x, lane = threadIdx.x;
    float cnt = fmaxf(counts[g], 1.0f);
    ps[lane] = pooled[g * DIM + lane] / cnt;
    __syncthreads();
#pragma unroll
    for (int rep = 0; rep < 2; ++rep) {
        int j = lane + rep * 64;
        float acc = b1[j];
        for (int k = 0; k < 64; ++k) acc += ps[k] * W1[k * HDIM + j];
        h1[j] = fmaxf(acc, 0.0f);
    }
    __syncthreads();
    float acc = b2[lane];
    for (int k = 0; k < 128; ++k) acc += h1[k] * W2[k * 64 + lane];
    float v = fmaxf(acc, 0.0f) * Wo[lane];
#pragma unroll
    for (int off = 32; off; off >>= 1) v += __shfl_down(v, off);
    if (lane == 0) out[g] = v + bo[0];
}

extern "C" void kernel_launch(void* const* d_in, const int* in_sizes, int n_in,
                              void* d_out, int out_size, void* d_ws, size_t ws_size,
                              hipStream_t stream) {
    const int* x = (const int*)d_in[0];
    const int* eidx = (const int*)d_in[1];
    const float* eattr = (const float*)d_in[2];
    const int* batch = (const int*)d_in[3];
    const float* emb = (const float*)d_in[4];
    const float* Wf = (const float*)d_in[5];
    const float* bf = (const float*)d_in[6];
    const float* Ws = (const float*)d_in[7];
    const float* bs = (const float*)d_in[8];
    const float* W1 = (const float*)d_in[9];
    const float* b1 = (const float*)d_in[10];
    const float* W2 = (const float*)d_in[11];
    const float* b2 = (const float*)d_in[12];
    const float* Wo = (const float*)d_in[13];
    const float* bo = (const float*)d_in[14];
    float* out = (float*)d_out;

    char* p = (char*)d_ws;
    float* h = (float*)p;       p += (size_t)N_NODES * DIM * 4;
    float* dstpack = (float*)p; p += (size_t)N_NODES * 2 * DIM * 4;
    float* srcpack = (float*)p; p += (size_t)N_NODES * 2 * DIM * 4;
    float* agg = (float*)p;     p += (size_t)N_NODES * DIM * 4;
    float* pooled = (float*)p;  p += (size_t)N_GRAPHS * DIM * 4;
    float* counts = (float*)p;  p += (size_t)N_GRAPHS * 4;
    short* wcat = (short*)p;    p += (size_t)NLAYER * 64 * 128 * 2;
    short* eattrP = (short*)p;  p += (size_t)NTILES * 4 * 64 * 8 * 2;  // 102.4 MB
    int* hist = (int*)p;        p += (size_t)N_NODES * 4;
    int* scanbuf = (int*)p;     p += (size_t)N_NODES * 4;
    int* blocksums = (int*)p;   p += 256 * 4;
    int* cursor = (int*)p;      p += (size_t)N_NODES * 4;
    int* perm = (int*)p;        p += (size_t)N_EDGES * 4;
    int* permSrc = (int*)p;     p += (size_t)N_EDGES * 4;
    int* permDst = (int*)p;     p += (size_t)N_EDGES * 4;
    size_t used_sorted = (size_t)(p - (char*)d_ws);

    bool sorted = used_sorted <= ws_size;

    const int SCAN_BLOCKS = (N_NODES + 255) / 256;  // 196
    const int NODEMM_BLOCKS = (N_NODES + 63) / 64;  // 782

    k_wcat<<<NLAYER * 64 * 128 / 256, 256, 0, stream>>>(Wf, Ws, wcat);
    if (sorted) {
        hipMemsetAsync(hist, 0, (size_t)N_NODES * 4, stream);
        k_hist<<<N_EDGES / 256, 256, 0, stream>>>(eidx, hist);
        k_scan1<<<SCAN_BLOCKS, 256, 0, stream>>>(hist, scanbuf, blocksums);
        k_scan2<<<1, 256, 0, stream>>>(blocksums, SCAN_BLOCKS);
        k_scan3<<<SCAN_BLOCKS, 256, 0, stream>>>(scanbuf, hist, blocksums, cursor);
        k_scatter<<<N_EDGES / 256, 256, 0, stream>>>(eidx, cursor, perm, permSrc, permDst);
        k_eprep2<<<NTILES * 64 / 256, 256, 0, stream>>>(eattr, perm, eattrP);
    }
    hipMemsetAsync(agg, 0, (size_t)N_NODES * DIM * 4, stream);
    for (int l = 0; l < NLAYER; ++l) {
        const float* Wfl = Wf + (size_t)l * ZDIM * DIM;
        const float* Wsl = Ws + (size_t)l * ZDIM * DIM;
        if (l == 0) {
            k_nodemm<2><<<NODEMM_BLOCKS, 256, 0, stream>>>(
                nullptr, h, nullptr, x, emb, Wfl, bf + l * DIM, Wsl, bs + l * DIM,
                dstpack, srcpack);
        } else {
            k_nodemm<1><<<NODEMM_BLOCKS, 256, 0, stream>>>(
                h, h, agg, nullptr, nullptr, Wfl, bf + l * DIM, Wsl, bs + l * DIM,
                dstpack, srcpack);
        }
        if (sorted) {
            k_edge_s<<<2048, 256, 0, stream>>>(permSrc, permDst, eattrP, dstpack, srcpack,
                                               wcat + (size_t)l * 64 * 128, agg);
        } else {
            k_edge_u<<<2048, 256, 0, stream>>>(eidx, eattr, dstpack, srcpack,
                                               wcat + (size_t)l * 64 * 128, agg);
        }
    }
    k_update<<<N_NODES * DIM / 256, 256, 0, stream>>>(h, agg);
    hipMemsetAsync(pooled, 0, ((size_t)N_GRAPHS * DIM + N_GRAPHS) * 4, stream);
    k_pool_s<<<(N_NODES + 255) / 256, 256, 0, stream>>>(h, batch, pooled, counts);
    k_mlp<<<N_GRAPHS, 64, 0, stream>>>(pooled, counts, W1, b1, W2, b2, Wo, bo, out);
}

// Round 8
// 900.523 us; speedup vs baseline: 2.5701x; 1.0209x over previous
//
#include <hip/hip_runtime.h>
#include <hip/hip_bf16.h>
#include <math.h>

#define N_NODES 50000
#define N_EDGES 800000
#define N_GRAPHS 256
#define DIM 64
#define EDIM 50
#define HDIM 128
#define NLAYER 4
#define ZDIM (2 * DIM + EDIM)  // 178
#define NTILES (N_EDGES / 32)  // 25000

typedef __attribute__((ext_vector_type(8))) short short8v;
typedef __attribute__((ext_vector_type(16))) float f32x16;

__device__ __forceinline__ float softplus_f(float x) {
    return fmaxf(x, 0.0f) + log1pf(__expf(-fabsf(x)));
}

__device__ __forceinline__ short cvt_bf16(float f) {
    __hip_bfloat16 h = __float2bfloat16(f);
    return *reinterpret_cast<short*>(&h);
}

// Weight tiles, column layout colv = g*64 + d (g: 0=sigmoid/Wf, 1=softplus/Ws)
// wcat[l][k][colv] = (k<50) ? W_g[l][128+k][d] : 0   (k padded to 64)
__global__ void k_wcat(const float* __restrict__ Wf, const float* __restrict__ Ws,
                       short* __restrict__ wcat) {
    int i = blockIdx.x * 256 + threadIdx.x;  // 4*64*128 = 32768
    int l = i >> 13;
    int rem = i & 8191;
    int k = rem >> 7;
    int colv = rem & 127;
    int g = colv >> 6, d = colv & 63;
    float v = 0.0f;
    if (k < 50) {
        const float* W = g ? Ws : Wf;
        v = W[((size_t)l * ZDIM + 128 + k) * 64 + d];
    }
    wcat[i] = cvt_bf16(v);
}

// ---------------- dst-sort (counting sort) ----------------
__global__ void k_hist(const int* __restrict__ eidx, int* __restrict__ hist) {
    int e = blockIdx.x * 256 + threadIdx.x;  // E exact
    atomicAdd(&hist[eidx[N_EDGES + e]], 1);
}

__global__ __launch_bounds__(256) void k_scan1(const int* __restrict__ hist,
                                               int* __restrict__ scanbuf,
                                               int* __restrict__ blocksums) {
    int tid = threadIdx.x;
    int i = blockIdx.x * 256 + tid;
    int v = (i < N_NODES) ? hist[i] : 0;
    int lane = tid & 63;
#pragma unroll
    for (int off = 1; off < 64; off <<= 1) {
        int u = __shfl_up(v, off);
        if (lane >= off) v += u;
    }
    __shared__ int wsum[4];
    if (lane == 63) wsum[tid >> 6] = v;
    __syncthreads();
    int w = tid >> 6;
    int add = 0;
#pragma unroll
    for (int k = 0; k < 3; ++k)
        if (k < w) add += wsum[k];
    v += add;
    if (i < N_NODES) scanbuf[i] = v;
    if (tid == 255) blocksums[blockIdx.x] = v;
}

__global__ __launch_bounds__(256) void k_scan2(int* __restrict__ blocksums, int nb) {
    int tid = threadIdx.x;
    int v = (tid < nb) ? blocksums[tid] : 0;
    int lane = tid & 63;
#pragma unroll
    for (int off = 1; off < 64; off <<= 1) {
        int u = __shfl_up(v, off);
        if (lane >= off) v += u;
    }
    __shared__ int wsum[4];
    if (lane == 63) wsum[tid >> 6] = v;
    __syncthreads();
    int w = tid >> 6;
    int add = 0;
#pragma unroll
    for (int k = 0; k < 3; ++k)
        if (k < w) add += wsum[k];
    v += add;
    if (tid < nb) blocksums[tid] = v;
}

__global__ void k_scan3(const int* __restrict__ scanbuf, const int* __restrict__ hist,
                        const int* __restrict__ blocksums, int* __restrict__ cursor) {
    int i = blockIdx.x * 256 + threadIdx.x;
    if (i >= N_NODES) return;
    int b = blockIdx.x;
    int off = b ? blocksums[b - 1] : 0;
    cursor[i] = scanbuf[i] - hist[i] + off;
}

__global__ void k_scatter(const int* __restrict__ eidx, int* __restrict__ cursor,
                          int* __restrict__ perm, int* __restrict__ permSrc,
                          int* __restrict__ permDst) {
    int e = blockIdx.x * 256 + threadIdx.x;
    int d = eidx[N_EDGES + e];
    int pos = atomicAdd(&cursor[d], 1);
    perm[pos] = e;
    permDst[pos] = d;
    permSrc[pos] = eidx[e];
}

// Sorted pack: thread = (tile, lane); handles all 4 kk fragments.
__global__ __launch_bounds__(256) void k_eprep2(const float* __restrict__ eattr,
                                                const int* __restrict__ perm,
                                                short* __restrict__ eattrP) {
    int i = blockIdx.x * 256 + threadIdx.x;  // over NTILES*64 = 1.6M
    int lane = i & 63;
    int tile = i >> 6;
    int pos = tile * 32 + (lane & 31);
    int h2 = lane >> 5;
    int edge = perm[pos];
    const float* erow = eattr + (size_t)edge * EDIM;  // 8B-aligned (200*edge)
    int k0 = 8 * h2;
    float2 v[12];
#pragma unroll
    for (int kk = 0; kk < 3; ++kk) {
#pragma unroll
        for (int p = 0; p < 4; ++p) {
            v[kk * 4 + p] = *(const float2*)(erow + k0 + 16 * kk + 2 * p);
        }
    }
    float2 t48 = make_float2(0.0f, 0.0f);
    if (h2 == 0) t48 = *(const float2*)(erow + 48);

    size_t fb = ((size_t)tile * 4) * 64 + lane;
#pragma unroll
    for (int kk = 0; kk < 3; ++kk) {
        short8v o;
#pragma unroll
        for (int p = 0; p < 4; ++p) {
            o[2 * p] = cvt_bf16(v[kk * 4 + p].x);
            o[2 * p + 1] = cvt_bf16(v[kk * 4 + p].y);
        }
        *(short8v*)&eattrP[(fb + (size_t)kk * 64) * 8] = o;
    }
    short8v o;
#pragma unroll
    for (int e = 0; e < 8; ++e) o[e] = 0;
    o[0] = cvt_bf16(t48.x);
    o[1] = cvt_bf16(t48.y);
    *(short8v*)&eattrP[(fb + 3 * 64) * 8] = o;
}

// Node-side matmuls, output layout [n][colv], colv = g*64+d.
// MODE 0: read h.  MODE 1: v=softplus(h+agg), write h, zero agg (fused update).
// MODE 2: v=emb[x[n]], write h (fused embed).
template <int MODE>
__global__ __launch_bounds__(256) void k_nodemm(
    const float* __restrict__ hin, float* __restrict__ hout, float* __restrict__ agg,
    const int* __restrict__ x, const float* __restrict__ emb,
    const float* __restrict__ Wf, const float* __restrict__ bf,
    const float* __restrict__ Ws, const float* __restrict__ bs,
    float* __restrict__ dstpack, float* __restrict__ srcpack) {
    __shared__ float hs[64 * 68];
    int tid = threadIdx.x;
    int w = tid >> 6, lane = tid & 63;
    int n0 = blockIdx.x * 64;
    for (int idx = tid; idx < 64 * 64; idx += 256) {
        int i = idx >> 6, k = idx & 63;
        int n = n0 + i;
        float v = 0.0f;
        if (n < N_NODES) {
            if (MODE == 0) {
                v = hin[(size_t)n * DIM + k];
            } else if (MODE == 1) {
                v = softplus_f(hin[(size_t)n * DIM + k] + agg[(size_t)n * DIM + k]);
                agg[(size_t)n * DIM + k] = 0.0f;
                hout[(size_t)n * DIM + k] = v;
            } else {
                v = emb[x[n] * DIM + k];
                hout[(size_t)n * DIM + k] = v;
            }
        }
        hs[i * 68 + k] = v;
    }
    __syncthreads();
    const float* Wsel = (w & 1) ? Ws : Wf;
    int row0 = (w < 2) ? 0 : 64;
    float wcol[64];
#pragma unroll
    for (int k = 0; k < 64; ++k) wcol[k] = Wsel[(row0 + k) * 64 + lane];
    float bias = (w == 0) ? bf[lane] : (w == 1) ? bs[lane] : 0.0f;
    float* outp = (w < 2) ? dstpack : srcpack;
    int colv = (w & 1) * 64 + lane;
    int nmax = min(64, N_NODES - n0);
    for (int i = 0; i < nmax; ++i) {
        float acc = bias;
#pragma unroll
        for (int k = 0; k < 64; k += 4) {
            float4 hv = *(const float4*)&hs[i * 68 + k];
            acc += hv.x * wcol[k] + hv.y * wcol[k + 1] + hv.z * wcol[k + 2] + hv.w * wcol[k + 3];
        }
        outp[(size_t)(n0 + i) * 128 + colv] = acc;
    }
}

// ---------------- sorted edge kernel, transposed MFMA: D[feat][edge] ----------------
// acc = mfma(W-frag as A, eattr-frag as B): per lane ONE edge (col = lane&31),
// 16 features in 4 runs of 4: feat = w*32 + 4*h2 + 8*q + i.
// waves 0,1 -> feats 0..63 (sigmoid); waves 2,3 -> feats 64..127 (softplus).
__global__ __launch_bounds__(256) void k_edge_s(
    const int* __restrict__ permSrc, const int* __restrict__ permDst,
    const short* __restrict__ eattrP, const float* __restrict__ dstpack,
    const float* __restrict__ srcpack, const short* __restrict__ wcat_l,
    float* __restrict__ agg) {
    __shared__ float msgV[2][64][34];  // [gate][d][edge], pitch 34 (bank-friendly)
    __shared__ int dsh[32];
    int tid = threadIdx.x;
    int w = tid >> 6;
    int lane = tid & 63;
    int c = lane & 31;   // edge within tile
    int h2 = lane >> 5;
    int col = w * 32 + c;  // feature colv for the weight A-fragment

    // Weight A-fragments: wfr[kk][j] = wcat[kk*16 + 8*h2 + j][col] (A row = feat)
    short8v wfr[4];
#pragma unroll
    for (int kk = 0; kk < 4; ++kk) {
#pragma unroll
        for (int e = 0; e < 8; ++e) {
            wfr[kk][e] = wcat_l[(kk * 16 + 8 * h2 + e) * 128 + col];
        }
    }

    for (int tile = blockIdx.x; tile < NTILES; tile += gridDim.x) {
        int e0 = tile * 32;
        int myedge = e0 + c;
        int tI = permDst[myedge];
        int sI = permSrc[myedge];
        if (tid < 32) dsh[tid] = tI;  // wave 0, lanes 0..31: c == tid

        // eattr B-fragments (B col = edge): same packed layout as before
        short8v efr[4];
#pragma unroll
        for (int kk = 0; kk < 4; ++kk) {
            efr[kk] = *(const short8v*)&eattrP[(((size_t)tile * 4 + kk) * 64 + lane) * 8];
        }

        f32x16 acc;
#pragma unroll
        for (int i = 0; i < 16; ++i) acc[i] = 0.0f;
#pragma unroll
        for (int kk = 0; kk < 4; ++kk) {
            acc = __builtin_amdgcn_mfma_f32_32x32x16_bf16(wfr[kk], efr[kk], acc, 0, 0, 0);
        }

        // Gathers: one row each from dstpack/srcpack, 4 dwordx4 per table
        const float* drow = dstpack + (((size_t)(unsigned)tI) << 7) + w * 32 + 4 * h2;
        const float* srow = srcpack + (((size_t)(unsigned)sI) << 7) + w * 32 + 4 * h2;
        float4 dv[4], sv[4];
#pragma unroll
        for (int q = 0; q < 4; ++q) dv[q] = *(const float4*)(drow + 8 * q);
#pragma unroll
        for (int q = 0; q < 4; ++q) sv[q] = *(const float4*)(srow + 8 * q);

        int dbase = (w & 1) * 32 + 4 * h2;  // d = dbase + 8*q + i  (d in 0..63)
        if (w < 2) {  // sigmoid, gate 0
#pragma unroll
            for (int q = 0; q < 4; ++q) {
#pragma unroll
                for (int i = 0; i < 4; ++i) {
                    float pre = acc[4 * q + i] + dv[q][i] + sv[q][i];
                    float e = __expf(-fabsf(pre));
                    float inv = __builtin_amdgcn_rcpf(1.0f + e);
                    msgV[0][dbase + 8 * q + i][c] = (pre >= 0.0f) ? inv : e * inv;
                }
            }
        } else {  // softplus, gate 1
#pragma unroll
            for (int q = 0; q < 4; ++q) {
#pragma unroll
                for (int i = 0; i < 4; ++i) {
                    float pre = acc[4 * q + i] + dv[q][i] + sv[q][i];
                    float e = __expf(-fabsf(pre));
                    msgV[1][dbase + 8 * q + i][c] = fmaxf(pre, 0.0f) + __logf(1.0f + e);
                }
            }
        }

        __syncthreads();

        // paired segmented scan: thread -> (d = tid&63, edges (tid>>6)*8 .. +8)
        {
            int d = tid & 63;
            int base = (tid >> 6) * 8;
            float m[8];
#pragma unroll
            for (int j2 = 0; j2 < 4; ++j2) {
                float2 a = *(const float2*)&msgV[0][d][base + 2 * j2];
                float2 b = *(const float2*)&msgV[1][d][base + 2 * j2];
                m[2 * j2] = a.x * b.x;
                m[2 * j2 + 1] = a.y * b.y;
            }
            float accum = 0.0f;
            int cur = dsh[base];
#pragma unroll
            for (int j = 0; j < 8; ++j) {
                int dn = dsh[base + j];
                if (dn != cur) {
                    unsafeAtomicAdd(&agg[(unsigned)((cur << 6) + d)], accum);
                    accum = 0.0f;
                    cur = dn;
                }
                accum += m[j];
            }
            unsafeAtomicAdd(&agg[(unsigned)((cur << 6) + d)], accum);
        }
        __syncthreads();
    }
}

// Unsorted fallback (only if ws too small for the sort buffers).
__global__ __launch_bounds__(256) void k_edge_u(
    const int* __restrict__ eidx, const float* __restrict__ eattr,
    const float* __restrict__ dstpack, const float* __restrict__ srcpack,
    const short* __restrict__ wcat_l, float* __restrict__ agg) {
    __shared__ float msgV[2][32][64];
    __shared__ int dsh[32], ssh[32];
    int tid = threadIdx.x;
    int w = tid >> 6;
    int lane = tid & 63;
    int c = lane & 31;
    int h2 = lane >> 5;
    int col = w * 32 + c;
    int dcol = (w & 1) * 32 + c;

    short8v bfr[4];
#pragma unroll
    for (int kk = 0; kk < 4; ++kk) {
#pragma unroll
        for (int e = 0; e < 8; ++e) bfr[kk][e] = wcat_l[(kk * 16 + 8 * h2 + e) * 128 + col];
    }

    for (int tile = blockIdx.x; tile < NTILES; tile += gridDim.x) {
        int e0 = tile * 32;
        if (lane < 32) {
            dsh[lane] = eidx[N_EDGES + e0 + lane];
            ssh[lane] = eidx[e0 + lane];
        }
        short8v afr[4];
        const float* erow = eattr + (size_t)(e0 + c) * EDIM;
#pragma unroll
        for (int kk = 0; kk < 3; ++kk) {
            int k0 = kk * 16 + 8 * h2;
#pragma unroll
            for (int p = 0; p < 4; ++p) {
                float2 v = *(const float2*)(erow + k0 + 2 * p);
                afr[kk][2 * p] = cvt_bf16(v.x);
                afr[kk][2 * p + 1] = cvt_bf16(v.y);
            }
        }
        {
            short8v a;
#pragma unroll
            for (int e = 0; e < 8; ++e) a[e] = 0;
            if (h2 == 0) {
                float2 v = *(const float2*)(erow + 48);
                a[0] = cvt_bf16(v.x);
                a[1] = cvt_bf16(v.y);
            }
            afr[3] = a;
        }
        f32x16 acc;
#pragma unroll
        for (int i = 0; i < 16; ++i) acc[i] = 0.0f;
#pragma unroll
        for (int kk = 0; kk < 4; ++kk)
            acc = __builtin_amdgcn_mfma_f32_32x32x16_bf16(afr[kk], bfr[kk], acc, 0, 0, 0);

        __builtin_amdgcn_wave_barrier();

#pragma unroll
        for (int grp = 0; grp < 2; ++grp) {
            int tI[8], sI[8];
            float dv[8], sv[8];
#pragma unroll
            for (int r = 0; r < 8; ++r) {
                int rr = grp * 8 + r;
                int row = (rr & 3) + 8 * (rr >> 2) + 4 * h2;
                tI[r] = dsh[row];
                sI[r] = ssh[row];
            }
#pragma unroll
            for (int r = 0; r < 8; ++r) {
                dv[r] = dstpack[(unsigned)((tI[r] << 7) + col)];
                sv[r] = srcpack[(unsigned)((sI[r] << 7) + col)];
            }
            float pre[8];
#pragma unroll
            for (int r = 0; r < 8; ++r) pre[r] = acc[grp * 8 + r] + dv[r] + sv[r];
            if (w < 2) {
#pragma unroll
                for (int r = 0; r < 8; ++r) {
                    int rr = grp * 8 + r;
                    int row = (rr & 3) + 8 * (rr >> 2) + 4 * h2;
                    float e = __expf(-fabsf(pre[r]));
                    float inv = __builtin_amdgcn_rcpf(1.0f + e);
                    msgV[0][row][dcol] = (pre[r] >= 0.0f) ? inv : e * inv;
                }
            } else {
#pragma unroll
                for (int r = 0; r < 8; ++r) {
                    int rr = grp * 8 + r;
                    int row = (rr & 3) + 8 * (rr >> 2) + 4 * h2;
                    float e = __expf(-fabsf(pre[r]));
                    msgV[1][row][dcol] = fmaxf(pre[r], 0.0f) + __logf(1.0f + e);
                }
            }
        }
        __syncthreads();
        {
            int d = tid & 63;
            int base = (tid >> 6) * 8;
#pragma unroll
            for (int j = 0; j < 8; ++j) {
                int row = base + j;
                float m = msgV[0][row][d] * msgV[1][row][d];
                unsafeAtomicAdd(&agg[(unsigned)((dsh[row] << 6) + d)], m);
            }
        }
        __syncthreads();
    }
}

// final update: h = softplus(h + agg); agg = 0
__global__ void k_update(float* __restrict__ h, float* __restrict__ agg) {
    int i = blockIdx.x * 256 + threadIdx.x;
    h[i] = softplus_f(h[i] + agg[i]);
    agg[i] = 0.0f;
}

// Sorted-batch pool: run-length accumulation, one atomic per graph transition.
__global__ __launch_bounds__(256) void k_pool_s(
    const float* __restrict__ h, const int* __restrict__ batch,
    float* __restrict__ pooled, float* __restrict__ counts) {
    int tid = threadIdx.x;
    int d = tid & 63;
    int strm = tid >> 6;
    int base = blockIdx.x * 256 + strm * 64;
    if (base >= N_NODES) return;
    int end = min(base + 64, N_NODES);
    float accum = 0.0f;
    int cnt = 0;
    int cur = batch[base];
#pragma unroll 4
    for (int n = base; n < end; ++n) {
        int g = batch[n];
        if (g != cur) {
            unsafeAtomicAdd(&pooled[cur * DIM + d], accum);
            if (d == 0) unsafeAtomicAdd(&counts[cur], (float)cnt);
            accum = 0.0f;
            cnt = 0;
            cur = g;
        }
        accum += h[(size_t)n * DIM + d];
        cnt++;
    }
    unsafeAtomicAdd(&pooled[cur * DIM + d], accum);
    if (d == 0) unsafeAtomicAdd(&counts[cur], (float)cnt);
}

__global__ __launch_bounds__(64) void k_mlp(
    const float* __restrict__ pooled, const float* __restrict__ counts,
    const float* __restrict__ W1, const float* __restrict__ b1,
    const float* __restrict__ W2, const float* __restrict__ b2,
    const float* __restrict__ Wo, const float* __restrict__ bo,
    float* __restrict__ out) {
    __shared__ float ps[64];
    __shared__ float h1[128];
    int g = blockIdx.x, lane = threadIdx.x;
    float cnt = fmaxf(counts[g], 1.0f);
    ps[lane] = pooled[g * DIM + lane] / cnt;
    __syncthreads();
#pragma unroll
    for (int rep = 0; rep < 2; ++rep) {
        int j = lane + rep * 64;
        float acc = b1[j];
        for (int k = 0; k < 64; ++k) acc += ps[k] * W1[k * HDIM + j];
        h1[j] = fmaxf(acc, 0.0f);
    }
    __syncthreads();
    float acc = b2[lane];
    for (int k = 0; k < 128; ++k) acc += h1[k] * W2[k * 64 + lane];
    float v = fmaxf(acc, 0.0f) * Wo[lane];
#pragma unroll
    for (int off = 32; off; off >>= 1) v += __shfl_down(v, off);
    if (lane == 0) out[g] = v + bo[0];
}

extern "C" void kernel_launch(void* const* d_in, const int* in_sizes, int n_in,
                              void* d_out, int out_size, void* d_ws, size_t ws_size,
                              hipStream_t stream) {
    const int* x = (const int*)d_in[0];
    const int* eidx = (const int*)d_in[1];
    const float* eattr = (const float*)d_in[2];
    const int* batch = (const int*)d_in[3];
    const float* emb = (const float*)d_in[4];
    const float* Wf = (const float*)d_in[5];
    const float* bf = (const float*)d_in[6];
    const float* Ws = (const float*)d_in[7];
    const float* bs = (const float*)d_in[8];
    const float* W1 = (const float*)d_in[9];
    const float* b1 = (const float*)d_in[10];
    const float* W2 = (const float*)d_in[11];
    const float* b2 = (const float*)d_in[12];
    const float* Wo = (const float*)d_in[13];
    const float* bo = (const float*)d_in[14];
    float* out = (float*)d_out;

    char* p = (char*)d_ws;
    float* h = (float*)p;       p += (size_t)N_NODES * DIM * 4;
    float* dstpack = (float*)p; p += (size_t)N_NODES * 2 * DIM * 4;
    float* srcpack = (float*)p; p += (size_t)N_NODES * 2 * DIM * 4;
    float* agg = (float*)p;     p += (size_t)N_NODES * DIM * 4;
    float* pooled = (float*)p;  p += (size_t)N_GRAPHS * DIM * 4;
    float* counts = (float*)p;  p += (size_t)N_GRAPHS * 4;
    short* wcat = (short*)p;    p += (size_t)NLAYER * 64 * 128 * 2;
    short* eattrP = (short*)p;  p += (size_t)NTILES * 4 * 64 * 8 * 2;  // 102.4 MB
    int* hist = (int*)p;        p += (size_t)N_NODES * 4;
    int* scanbuf = (int*)p;     p += (size_t)N_NODES * 4;
    int* blocksums = (int*)p;   p += 256 * 4;
    int* cursor = (int*)p;      p += (size_t)N_NODES * 4;
    int* perm = (int*)p;        p += (size_t)N_EDGES * 4;
    int* permSrc = (int*)p;     p += (size_t)N_EDGES * 4;
    int* permDst = (int*)p;     p += (size_t)N_EDGES * 4;
    size_t used_sorted = (size_t)(p - (char*)d_ws);

    bool sorted = used_sorted <= ws_size;

    const int SCAN_BLOCKS = (N_NODES + 255) / 256;  // 196
    const int NODEMM_BLOCKS = (N_NODES + 63) / 64;  // 782

    k_wcat<<<NLAYER * 64 * 128 / 256, 256, 0, stream>>>(Wf, Ws, wcat);
    if (sorted) {
        hipMemsetAsync(hist, 0, (size_t)N_NODES * 4, stream);
        k_hist<<<N_EDGES / 256, 256, 0, stream>>>(eidx, hist);
        k_scan1<<<SCAN_BLOCKS, 256, 0, stream>>>(hist, scanbuf, blocksums);
        k_scan2<<<1, 256, 0, stream>>>(blocksums, SCAN_BLOCKS);
        k_scan3<<<SCAN_BLOCKS, 256, 0, stream>>>(scanbuf, hist, blocksums, cursor);
        k_scatter<<<N_EDGES / 256, 256, 0, stream>>>(eidx, cursor, perm, permSrc, permDst);
        k_eprep2<<<NTILES * 64 / 256, 256, 0, stream>>>(eattr, perm, eattrP);
    }
    hipMemsetAsync(agg, 0, (size_t)N_NODES * DIM * 4, stream);
    for (int l = 0; l < NLAYER; ++l) {
        const float* Wfl = Wf + (size_t)l * ZDIM * DIM;
        const float* Wsl = Ws + (size_t)l * ZDIM * DIM;
        if (l == 0) {
            k_nodemm<2><<<NODEMM_BLOCKS, 256, 0, stream>>>(
                nullptr, h, nullptr, x, emb, Wfl, bf + l * DIM, Wsl, bs + l * DIM,
                dstpack, srcpack);
        } else {
            k_nodemm<1><<<NODEMM_BLOCKS, 256, 0, stream>>>(
                h, h, agg, nullptr, nullptr, Wfl, bf + l * DIM, Wsl, bs + l * DIM,
                dstpack, srcpack);
        }
        if (sorted) {
            k_edge_s<<<2048, 256, 0, stream>>>(permSrc, permDst, eattrP, dstpack, srcpack,
                                               wcat + (size_t)l * 64 * 128, agg);
        } else {
            k_edge_u<<<2048, 256, 0, stream>>>(eidx, eattr, dstpack, srcpack,
                                               wcat + (size_t)l * 64 * 128, agg);
        }
    }
    k_update<<<N_NODES * DIM / 256, 256, 0, stream>>>(h, agg);
    hipMemsetAsync(pooled, 0, ((size_t)N_GRAPHS * DIM + N_GRAPHS) * 4, stream);
    k_pool_s<<<(N_NODES + 255) / 256, 256, 0, stream>>>(h, batch, pooled, counts);
    k_mlp<<<N_GRAPHS, 64, 0, stream>>>(pooled, counts, W1, b1, W2, b2, Wo, bo, out);
}